// Round 2
// baseline (1952.111 us; speedup 1.0000x reference)
//
#include <hip/hip_runtime.h>
#include <hip/hip_bf16.h>

#define NN 50000
#define NE 800000

typedef __hip_bfloat16 bf16;
typedef __attribute__((ext_vector_type(8))) short bf16x8s;   // 8 bf16 = 4 VGPRs
typedef __attribute__((ext_vector_type(4))) float f32x4;

// ---- workspace layout (bytes) ----
#define OFF_E      0L            // e buffer      [NE,64] bf16 = 102,400,000
#define OFF_MSG    102400000L    // msg buffer    [NE,64] bf16  (also hosts cvt inputs pre-loop)
#define OFF_CVT_H  102400000L    //   h_in bf16 [NN,128] = 12,800,000
#define OFF_CVT_E  115200000L    //   e_in bf16 [NE,16]  = 25,600,000
#define OFF_CVT_P  140800000L    //   p_in bf16 [NN,16]  =  1,600,000
#define OFF_H      204800000L    // h             [NN,64] bf16
#define OFF_P      211200000L    // p
#define OFF_HAGG   217600000L    // h_agg
#define OFF_PAGG   224000000L    // p_agg
#define OFF_WFMT   230400000L    // formatted weights, 258048 bf16 = 516,096 B
#define OFF_ROWPTR 230916096L    // (NN+1) int
#define OFF_COLIDX 231116104L    // NE int
#define OFF_CNT    234316104L    // NN int
// total ~234.6 MB

// ---- formatted-weight element offsets ----
#define WOFF_HE 0
#define WOFF_EE 8192
#define WOFF_PE 10240
#define WOFF_HM 12288       // 4 x 20480
#define WOFF_HU 94208       // 4 x 8192
#define WOFF_EU 126976      // 4 x 12288
#define WOFF_PM 176128      // 4 x 12288
#define WOFF_PU 225280      // 4 x 8192

// gather modes
#define M_EMB16  0   // A0 rows of 16 (K=16 zero-padded to 32)
#define M_EMB128 1   // A0 rows of 128
#define M_NODE2  2   // [A0[row], A1[row]]           K=128
#define M_EDGE3  3   // [A0[send], A0[rec], A1[row]] K=192
#define M_HMSG   4   // [A0[s],A1[s],A0[r],A1[r],A2[row]] K=320

// ======================= fp32 -> bf16 conversion =======================
__global__ __launch_bounds__(256) void cvt_k(const float* __restrict__ src,
                                             bf16* __restrict__ dst, int n4)
{
    int i = blockIdx.x*256 + threadIdx.x;
    if (i < n4) {
        float4 v = ((const float4*)src)[i];
        dst[i*4+0] = __float2bfloat16(v.x);
        dst[i*4+1] = __float2bfloat16(v.y);
        dst[i*4+2] = __float2bfloat16(v.z);
        dst[i*4+3] = __float2bfloat16(v.w);
    }
}

// ======================= weight formatting (fp32 -> bf16 B-fragments) ==
// Bfmt[((c*4+t)*64 + lane)*8 + j] = W[c*32 + (lane>>4)*8 + j][t*16 + (lane&15)]
__global__ __launch_bounds__(256) void wfmt_k(
    const float* __restrict__ he, const float* __restrict__ ee, const float* __restrict__ pe,
    const float* __restrict__ hm, const float* __restrict__ hu, const float* __restrict__ eu,
    const float* __restrict__ pm, const float* __restrict__ pu, bf16* __restrict__ wf)
{
    int s = blockIdx.x;
    const float* src; int Ksrc, Kpad; long doff;
    if      (s == 0) { src = he; Ksrc = 128; Kpad = 128; doff = WOFF_HE; }
    else if (s == 1) { src = ee; Ksrc = 16;  Kpad = 32;  doff = WOFF_EE; }
    else if (s == 2) { src = pe; Ksrc = 16;  Kpad = 32;  doff = WOFF_PE; }
    else if (s < 7)  { int i = s - 3;  src = hm + (long)i*320*64; Ksrc = 320; Kpad = 320; doff = WOFF_HM + (long)i*20480; }
    else if (s < 11) { int i = s - 7;  src = hu + (long)i*128*64; Ksrc = 128; Kpad = 128; doff = WOFF_HU + (long)i*8192; }
    else if (s < 15) { int i = s - 11; src = eu + (long)i*192*64; Ksrc = 192; Kpad = 192; doff = WOFF_EU + (long)i*12288; }
    else if (s < 19) { int i = s - 15; src = pm + (long)i*192*64; Ksrc = 192; Kpad = 192; doff = WOFF_PM + (long)i*12288; }
    else             { int i = s - 19; src = pu + (long)i*128*64; Ksrc = 128; Kpad = 128; doff = WOFF_PU + (long)i*8192; }
    int total = Kpad * 64;
    for (int idx = threadIdx.x; idx < total; idx += blockDim.x) {
        int j = idx & 7, l = (idx >> 3) & 63, ct = idx >> 9;
        int c = ct >> 2, t = ct & 3;
        int k = c*32 + (l >> 4)*8 + j;
        int n = t*16 + (l & 15);
        wf[doff + idx] = (k < Ksrc) ? __float2bfloat16(src[(long)k*64 + n])
                                    : __float2bfloat16(0.0f);
    }
}

// ======================= CSR build =======================
__global__ __launch_bounds__(256) void hist_k(const int* __restrict__ rec, int* __restrict__ cnt)
{
    int e = blockIdx.x*256 + threadIdx.x;
    if (e < NE) atomicAdd(&cnt[rec[e]], 1);
}

__global__ __launch_bounds__(1024) void scan_k(const int* __restrict__ cnt, int* __restrict__ rowptr)
{
    __shared__ int sdata[1024];
    __shared__ int s_carry;
    int tid = threadIdx.x;
    if (tid == 0) { s_carry = 0; rowptr[0] = 0; }
    __syncthreads();
    for (int base = 0; base < NN; base += 1024) {
        int i = base + tid;
        int v = (i < NN) ? cnt[i] : 0;
        sdata[tid] = v;
        __syncthreads();
        for (int off = 1; off < 1024; off <<= 1) {
            int t = (tid >= off) ? sdata[tid - off] : 0;
            __syncthreads();
            sdata[tid] += t;
            __syncthreads();
        }
        int total = sdata[1023];
        if (i < NN) rowptr[i + 1] = s_carry + sdata[tid];
        __syncthreads();
        if (tid == 0) s_carry += total;
        __syncthreads();
    }
}

__global__ __launch_bounds__(256) void scatter_k(const int* __restrict__ rec,
    const int* __restrict__ rowptr, int* __restrict__ cursor, int* __restrict__ colidx)
{
    int e = blockIdx.x*256 + threadIdx.x;
    if (e < NE) {
        int r = rec[e];
        int pos = atomicAdd(&cursor[r], 1);
        colidx[rowptr[r] + pos] = e;
    }
}

// ======================= CSR aggregation (segment_sum) =======================
__global__ __launch_bounds__(256) void agg_k(const bf16* __restrict__ msg,
    const int* __restrict__ rowptr, const int* __restrict__ colidx, bf16* __restrict__ out)
{
    int node = blockIdx.x*4 + (threadIdx.x >> 6);
    int lane = threadIdx.x & 63;
    if (node >= NN) return;
    int beg = rowptr[node], end = rowptr[node + 1];
    float acc = 0.0f;
    for (int j = beg; j < end; ++j) {
        int e = colidx[j];
        acc += __bfloat162float(msg[(long)e*64 + lane]);
    }
    out[(long)node*64 + lane] = __float2bfloat16(acc);
}

// ======================= fused gather + GEMM (MFMA) =======================
// Per block: 256 rows. Per wave: 64 rows = 4 M-tiles of 16. N=64 = 4 tiles.
template <int MODE, int KCH>
__global__ __launch_bounds__(256) void gemm_k(
    const bf16* __restrict__ A0, const bf16* __restrict__ A1, const bf16* __restrict__ A2,
    const int* __restrict__ send, const int* __restrict__ rec,
    const bf16* __restrict__ wf, const float* __restrict__ bias,
    bf16* __restrict__ out, float* __restrict__ out2, int n_rows)
{
    __shared__ __align__(16) bf16 lds_w[KCH * 2048];
    int tid = threadIdx.x;
    {   // stage formatted weights to LDS (KCH*4096 bytes)
        const int4* src = (const int4*)wf;
        int4* dst = (int4*)lds_w;
        #pragma unroll
        for (int i = tid; i < KCH*256; i += 256) dst[i] = src[i];
    }
    __syncthreads();

    int lane = tid & 63, wv = tid >> 6;
    int l15 = lane & 15, q = lane >> 4;
    long row_base = (long)blockIdx.x*256 + wv*64;

    int eclamp[4], sidx[4], ridx[4];
    #pragma unroll
    for (int et = 0; et < 4; ++et) {
        long r = row_base + et*16 + l15;
        int rc = (r < n_rows) ? (int)r : (n_rows - 1);
        eclamp[et] = rc;
        if (MODE >= M_EDGE3) { sidx[et] = send[rc]; ridx[et] = rec[rc]; }
    }

    float bv[4];
    #pragma unroll
    for (int t = 0; t < 4; ++t) bv[t] = bias[t*16 + l15];

    f32x4 acc[4][4];
    #pragma unroll
    for (int et = 0; et < 4; ++et)
        #pragma unroll
        for (int t = 0; t < 4; ++t) {
            acc[et][t][0] = bv[t]; acc[et][t][1] = bv[t];
            acc[et][t][2] = bv[t]; acc[et][t][3] = bv[t];
        }

    #pragma unroll
    for (int c = 0; c < KCH; ++c) {
        bf16x8s af[4];
        #pragma unroll
        for (int et = 0; et < 4; ++et) {
            bf16x8s v = {0,0,0,0,0,0,0,0};
            if constexpr (MODE == M_EMB16) {
                if (q < 2) v = *(const bf16x8s*)(A0 + (long)eclamp[et]*16 + q*8);
            } else if constexpr (MODE == M_EMB128) {
                v = *(const bf16x8s*)(A0 + (long)eclamp[et]*128 + c*32 + q*8);
            } else if constexpr (MODE == M_NODE2) {
                int seg = c >> 1; int off = ((c & 1) << 5) + (q << 3);
                const bf16* b = (seg == 0 ? A0 : A1) + (long)eclamp[et]*64;
                v = *(const bf16x8s*)(b + off);
            } else if constexpr (MODE == M_EDGE3) {
                int seg = c >> 1; int off = ((c & 1) << 5) + (q << 3);
                const bf16* b = (seg == 0) ? A0 + (long)sidx[et]*64
                              : (seg == 1) ? A0 + (long)ridx[et]*64
                                           : A1 + (long)eclamp[et]*64;
                v = *(const bf16x8s*)(b + off);
            } else { // M_HMSG
                int seg = c >> 1; int off = ((c & 1) << 5) + (q << 3);
                const bf16* b = (seg == 0) ? A0 + (long)sidx[et]*64
                              : (seg == 1) ? A1 + (long)sidx[et]*64
                              : (seg == 2) ? A0 + (long)ridx[et]*64
                              : (seg == 3) ? A1 + (long)ridx[et]*64
                                           : A2 + (long)eclamp[et]*64;
                v = *(const bf16x8s*)(b + off);
            }
            af[et] = v;
        }
        #pragma unroll
        for (int t = 0; t < 4; ++t) {
            bf16x8s bfv = *(const bf16x8s*)(lds_w + ((long)(c*4 + t)*64 + lane)*8);
            #pragma unroll
            for (int et = 0; et < 4; ++et)
                acc[et][t] = __builtin_amdgcn_mfma_f32_16x16x32_bf16(af[et], bfv, acc[et][t], 0, 0, 0);
        }
    }

    // D layout: row = q*4 + reg, col = t*16 + l15
    #pragma unroll
    for (int et = 0; et < 4; ++et) {
        #pragma unroll
        for (int r = 0; r < 4; ++r) {
            long row = row_base + et*16 + q*4 + r;
            if (row < n_rows) {
                #pragma unroll
                for (int t = 0; t < 4; ++t) {
                    float fv = acc[et][t][r];
                    out[row*64 + t*16 + l15] = __float2bfloat16(fv);
                    if (out2) out2[row*64 + t*16 + l15] = fv;
                }
            }
        }
    }
}

// ======================= launch =======================
extern "C" void kernel_launch(void* const* d_in, const int* in_sizes, int n_in,
                              void* d_out, int out_size, void* d_ws, size_t ws_size,
                              hipStream_t stream)
{
    (void)in_sizes; (void)n_in; (void)out_size; (void)ws_size;
    const float* h_in = (const float*)d_in[0];
    const float* e_in = (const float*)d_in[1];
    const float* p_in = (const float*)d_in[2];
    const int*  ei   = (const int*)d_in[3];
    const int* send = ei;
    const int* rec  = ei + NE;
    const float* he_W = (const float*)d_in[4];  const float* he_b = (const float*)d_in[5];
    const float* ee_W = (const float*)d_in[6];  const float* ee_b = (const float*)d_in[7];
    const float* pe_W = (const float*)d_in[8];  const float* pe_b = (const float*)d_in[9];
    const float* hm_W = (const float*)d_in[10]; const float* hm_b = (const float*)d_in[11];
    const float* hu_W = (const float*)d_in[12]; const float* hu_b = (const float*)d_in[13];
    const float* eu_W = (const float*)d_in[14]; const float* eu_b = (const float*)d_in[15];
    const float* pm_W = (const float*)d_in[16]; const float* pm_b = (const float*)d_in[17];
    const float* pu_W = (const float*)d_in[18]; const float* pu_b = (const float*)d_in[19];

    char* ws = (char*)d_ws;
    bf16* e_buf = (bf16*)(ws + OFF_E);
    bf16* msg   = (bf16*)(ws + OFF_MSG);
    bf16* cvt_h = (bf16*)(ws + OFF_CVT_H);
    bf16* cvt_e = (bf16*)(ws + OFF_CVT_E);
    bf16* cvt_p = (bf16*)(ws + OFF_CVT_P);
    bf16* h     = (bf16*)(ws + OFF_H);
    bf16* p     = (bf16*)(ws + OFF_P);
    bf16* hagg  = (bf16*)(ws + OFF_HAGG);
    bf16* pagg  = (bf16*)(ws + OFF_PAGG);
    bf16* wf    = (bf16*)(ws + OFF_WFMT);
    int* rowptr = (int*)(ws + OFF_ROWPTR);
    int* colidx = (int*)(ws + OFF_COLIDX);
    int* cnt    = (int*)(ws + OFF_CNT);
    float* dout = (float*)d_out;

    const int EB = NE / 256;          // 3125 blocks, exact
    const int NB = (NN + 255) / 256;  // 196 blocks

    // CSR build (by rec)
    hipMemsetAsync(cnt, 0, NN * sizeof(int), stream);
    hist_k<<<EB, 256, 0, stream>>>(rec, cnt);
    scan_k<<<1, 1024, 0, stream>>>(cnt, rowptr);
    hipMemsetAsync(cnt, 0, NN * sizeof(int), stream);
    scatter_k<<<EB, 256, 0, stream>>>(rec, rowptr, cnt, colidx);

    // input conversion fp32 -> bf16 (into the msg region; dead until the layer loop)
    cvt_k<<<(NN*128/4 + 255)/256, 256, 0, stream>>>(h_in, cvt_h, NN*128/4);
    cvt_k<<<(NE*16/4 + 255)/256, 256, 0, stream>>>(e_in, cvt_e, NE*16/4);
    cvt_k<<<(NN*16/4 + 255)/256, 256, 0, stream>>>(p_in, cvt_p, NN*16/4);

    // weight formatting
    wfmt_k<<<23, 256, 0, stream>>>(he_W, ee_W, pe_W, hm_W, hu_W, eu_W, pm_W, pu_W, wf);

    // embeddings
    gemm_k<M_EMB128, 4><<<NB, 256, 0, stream>>>(cvt_h, nullptr, nullptr, nullptr, nullptr,
        wf + WOFF_HE, he_b, h, nullptr, NN);
    gemm_k<M_EMB16, 1><<<EB, 256, 0, stream>>>(cvt_e, nullptr, nullptr, nullptr, nullptr,
        wf + WOFF_EE, ee_b, e_buf, nullptr, NE);
    gemm_k<M_EMB16, 1><<<NB, 256, 0, stream>>>(cvt_p, nullptr, nullptr, nullptr, nullptr,
        wf + WOFF_PE, pe_b, p, nullptr, NN);

    for (int i = 0; i < 4; ++i) {
        // h_msg = [h[s],p[s],h[r],p[r],e] @ hm_W[i]
        gemm_k<M_HMSG, 10><<<EB, 256, 0, stream>>>(h, p, e_buf, send, rec,
            wf + WOFF_HM + (long)i*20480, hm_b + i*64, msg, nullptr, NE);
        agg_k<<<NN/4, 256, 0, stream>>>(msg, rowptr, colidx, hagg);
        // h = [h, h_agg] @ hu_W[i]
        gemm_k<M_NODE2, 4><<<NB, 256, 0, stream>>>(h, hagg, nullptr, nullptr, nullptr,
            wf + WOFF_HU + (long)i*8192, hu_b + i*64, h, (i == 3) ? dout : nullptr, NN);
        // e = [h[s], h[r], e] @ eu_W[i]   (in-place per-row safe)
        gemm_k<M_EDGE3, 6><<<EB, 256, 0, stream>>>(h, e_buf, nullptr, send, rec,
            wf + WOFF_EU + (long)i*12288, eu_b + i*64, e_buf, nullptr, NE);
        // p_msg = [p[s], p[r], e_new] @ pm_W[i]
        gemm_k<M_EDGE3, 6><<<EB, 256, 0, stream>>>(p, e_buf, nullptr, send, rec,
            wf + WOFF_PM + (long)i*12288, pm_b + i*64, msg, nullptr, NE);
        agg_k<<<NN/4, 256, 0, stream>>>(msg, rowptr, colidx, pagg);
        // p = [p, p_agg] @ pu_W[i]
        gemm_k<M_NODE2, 4><<<NB, 256, 0, stream>>>(p, pagg, nullptr, nullptr, nullptr,
            wf + WOFF_PU + (long)i*8192, pu_b + i*64, p, (i == 3) ? dout + (long)NN*64 : nullptr, NN);
    }
}

// Round 3
// 1826.315 us; speedup vs baseline: 1.0689x; 1.0689x over previous
//
#include <hip/hip_runtime.h>
#include <hip/hip_bf16.h>

#define NN 50000
#define NE 800000

typedef __hip_bfloat16 bf16;
typedef __attribute__((ext_vector_type(8))) short bf16x8s;   // 8 bf16 = 4 VGPRs
typedef __attribute__((ext_vector_type(4))) float f32x4;

// ---- workspace layout (bytes) ----
#define OFF_E      0L            // e buffer (SORTED edge order) [NE,64] bf16
#define OFF_MSG    102400000L    // msg buffer (SORTED) [NE,64] bf16 (hosts cvt inputs pre-loop)
#define OFF_CVT_H  102400000L    //   h_in bf16 [NN,128]
#define OFF_CVT_E  115200000L    //   e_in bf16 [NE,16]
#define OFF_CVT_P  140800000L    //   p_in bf16 [NN,16]
#define OFF_H      204800000L    // h             [NN,64] bf16
#define OFF_P      211200000L    // p
#define OFF_HAGG   217600000L    // h_agg
#define OFF_PAGG   224000000L    // p_agg
#define OFF_WFMT   230400000L    // formatted weights, 258048 bf16
#define OFF_ROWPTR 230916096L    // (NN+1) int
#define OFF_COLIDX 231116104L    // NE int  (sorted-pos j -> original edge id)
#define OFF_CNT    234316104L    // NN int
// total ~234.6 MB

// ---- formatted-weight element offsets ----
#define WOFF_HE 0
#define WOFF_EE 8192
#define WOFF_PE 10240
#define WOFF_HM 12288       // 4 x 20480
#define WOFF_HU 94208       // 4 x 8192
#define WOFF_EU 126976      // 4 x 12288
#define WOFF_PM 176128      // 4 x 12288
#define WOFF_PU 225280      // 4 x 8192

// gather modes
#define M_EMB16  0   // A0 rows of 16 (K=16 zero-padded to 32), direct rows
#define M_EMB128 1   // A0 rows of 128, direct rows
#define M_NODE2  2   // [A0[row], A1[row]]           K=128
#define M_EDGE3  3   // [A0[s], A0[r], A1[j]] K=192, s/r via gmap indirection
#define M_HMSG   4   // [A0[s],A1[s],A0[r],A1[r],A2[j]] K=320
#define M_EMB16G 5   // A0 rows of 16 gathered via gmap (sorted e embedding)

// ======================= fp32 -> bf16 conversion =======================
__global__ __launch_bounds__(256) void cvt_k(const float* __restrict__ src,
                                             bf16* __restrict__ dst, int n4)
{
    int i = blockIdx.x*256 + threadIdx.x;
    if (i < n4) {
        float4 v = ((const float4*)src)[i];
        dst[i*4+0] = __float2bfloat16(v.x);
        dst[i*4+1] = __float2bfloat16(v.y);
        dst[i*4+2] = __float2bfloat16(v.z);
        dst[i*4+3] = __float2bfloat16(v.w);
    }
}

// ======================= weight formatting (fp32 -> bf16 B-fragments) ==
// Bfmt[((c*4+t)*64 + lane)*8 + j] = W[c*32 + (lane>>4)*8 + j][t*16 + (lane&15)]
__global__ __launch_bounds__(256) void wfmt_k(
    const float* __restrict__ he, const float* __restrict__ ee, const float* __restrict__ pe,
    const float* __restrict__ hm, const float* __restrict__ hu, const float* __restrict__ eu,
    const float* __restrict__ pm, const float* __restrict__ pu, bf16* __restrict__ wf)
{
    int s = blockIdx.x;
    const float* src; int Ksrc, Kpad; long doff;
    if      (s == 0) { src = he; Ksrc = 128; Kpad = 128; doff = WOFF_HE; }
    else if (s == 1) { src = ee; Ksrc = 16;  Kpad = 32;  doff = WOFF_EE; }
    else if (s == 2) { src = pe; Ksrc = 16;  Kpad = 32;  doff = WOFF_PE; }
    else if (s < 7)  { int i = s - 3;  src = hm + (long)i*320*64; Ksrc = 320; Kpad = 320; doff = WOFF_HM + (long)i*20480; }
    else if (s < 11) { int i = s - 7;  src = hu + (long)i*128*64; Ksrc = 128; Kpad = 128; doff = WOFF_HU + (long)i*8192; }
    else if (s < 15) { int i = s - 11; src = eu + (long)i*192*64; Ksrc = 192; Kpad = 192; doff = WOFF_EU + (long)i*12288; }
    else if (s < 19) { int i = s - 15; src = pm + (long)i*192*64; Ksrc = 192; Kpad = 192; doff = WOFF_PM + (long)i*12288; }
    else             { int i = s - 19; src = pu + (long)i*128*64; Ksrc = 128; Kpad = 128; doff = WOFF_PU + (long)i*8192; }
    int total = Kpad * 64;
    for (int idx = threadIdx.x; idx < total; idx += blockDim.x) {
        int j = idx & 7, l = (idx >> 3) & 63, ct = idx >> 9;
        int c = ct >> 2, t = ct & 3;
        int k = c*32 + (l >> 4)*8 + j;
        int n = t*16 + (l & 15);
        wf[doff + idx] = (k < Ksrc) ? __float2bfloat16(src[(long)k*64 + n])
                                    : __float2bfloat16(0.0f);
    }
}

// ======================= CSR build =======================
__global__ __launch_bounds__(256) void hist_k(const int* __restrict__ rec, int* __restrict__ cnt)
{
    int e = blockIdx.x*256 + threadIdx.x;
    if (e < NE) atomicAdd(&cnt[rec[e]], 1);
}

__global__ __launch_bounds__(1024) void scan_k(const int* __restrict__ cnt, int* __restrict__ rowptr)
{
    __shared__ int sdata[1024];
    __shared__ int s_carry;
    int tid = threadIdx.x;
    if (tid == 0) { s_carry = 0; rowptr[0] = 0; }
    __syncthreads();
    for (int base = 0; base < NN; base += 1024) {
        int i = base + tid;
        int v = (i < NN) ? cnt[i] : 0;
        sdata[tid] = v;
        __syncthreads();
        for (int off = 1; off < 1024; off <<= 1) {
            int t = (tid >= off) ? sdata[tid - off] : 0;
            __syncthreads();
            sdata[tid] += t;
            __syncthreads();
        }
        int total = sdata[1023];
        if (i < NN) rowptr[i + 1] = s_carry + sdata[tid];
        __syncthreads();
        if (tid == 0) s_carry += total;
        __syncthreads();
    }
}

__global__ __launch_bounds__(256) void scatter_k(const int* __restrict__ rec,
    const int* __restrict__ rowptr, int* __restrict__ cursor, int* __restrict__ colidx)
{
    int e = blockIdx.x*256 + threadIdx.x;
    if (e < NE) {
        int r = rec[e];
        int pos = atomicAdd(&cursor[r], 1);
        colidx[rowptr[r] + pos] = e;
    }
}

// ======================= CSR aggregation — msg is SORTED, pure stream ====
__global__ __launch_bounds__(256) void agg_k(const bf16* __restrict__ msg,
    const int* __restrict__ rowptr, bf16* __restrict__ out)
{
    int node = blockIdx.x*4 + (threadIdx.x >> 6);
    int lane = threadIdx.x & 63;
    if (node >= NN) return;
    int beg = rowptr[node], end = rowptr[node + 1];
    float acc = 0.0f;
    for (int j = beg; j < end; ++j)
        acc += __bfloat162float(msg[(long)j*64 + lane]);
    out[(long)node*64 + lane] = __float2bfloat16(acc);
}

// ======================= fused gather + GEMM (MFMA) =======================
// Per block: 256 rows. Per wave: 64 rows = 4 M-tiles of 16. N=64 = 4 tiles.
// Edge modes operate on SORTED edge positions j; original edge id = gmap[j].
template <int MODE, int KCH>
__global__ __launch_bounds__(256) void gemm_k(
    const bf16* __restrict__ A0, const bf16* __restrict__ A1, const bf16* __restrict__ A2,
    const int* __restrict__ send, const int* __restrict__ rec, const int* __restrict__ gmap,
    const bf16* __restrict__ wf, const float* __restrict__ bias,
    bf16* __restrict__ out, float* __restrict__ out2, int n_rows)
{
    __shared__ __align__(16) bf16 lds_w[KCH * 2048];
    int tid = threadIdx.x;
    {   // stage formatted weights to LDS (KCH*4096 bytes)
        const int4* src = (const int4*)wf;
        int4* dst = (int4*)lds_w;
        #pragma unroll
        for (int i = tid; i < KCH*256; i += 256) dst[i] = src[i];
    }
    __syncthreads();

    int lane = tid & 63, wv = tid >> 6;
    int l15 = lane & 15, q = lane >> 4;
    long row_base = (long)blockIdx.x*256 + wv*64;

    int eclamp[4], sidx[4], ridx[4];
    #pragma unroll
    for (int et = 0; et < 4; ++et) {
        long r = row_base + et*16 + l15;
        int rc = (r < n_rows) ? (int)r : (n_rows - 1);
        eclamp[et] = rc;
        if constexpr (MODE == M_EDGE3 || MODE == M_HMSG) {
            int em = gmap[rc];
            sidx[et] = send[em]; ridx[et] = rec[em];
        } else if constexpr (MODE == M_EMB16G) {
            sidx[et] = gmap[rc];
        }
    }

    float bv[4];
    #pragma unroll
    for (int t = 0; t < 4; ++t) bv[t] = bias[t*16 + l15];

    f32x4 acc[4][4];
    #pragma unroll
    for (int et = 0; et < 4; ++et)
        #pragma unroll
        for (int t = 0; t < 4; ++t) {
            acc[et][t][0] = bv[t]; acc[et][t][1] = bv[t];
            acc[et][t][2] = bv[t]; acc[et][t][3] = bv[t];
        }

    #pragma unroll
    for (int c = 0; c < KCH; ++c) {
        bf16x8s af[4];
        #pragma unroll
        for (int et = 0; et < 4; ++et) {
            bf16x8s v = {0,0,0,0,0,0,0,0};
            if constexpr (MODE == M_EMB16) {
                if (q < 2) v = *(const bf16x8s*)(A0 + (long)eclamp[et]*16 + q*8);
            } else if constexpr (MODE == M_EMB16G) {
                if (q < 2) v = *(const bf16x8s*)(A0 + (long)sidx[et]*16 + q*8);
            } else if constexpr (MODE == M_EMB128) {
                v = *(const bf16x8s*)(A0 + (long)eclamp[et]*128 + c*32 + q*8);
            } else if constexpr (MODE == M_NODE2) {
                int seg = c >> 1; int off = ((c & 1) << 5) + (q << 3);
                const bf16* b = (seg == 0 ? A0 : A1) + (long)eclamp[et]*64;
                v = *(const bf16x8s*)(b + off);
            } else if constexpr (MODE == M_EDGE3) {
                int seg = c >> 1; int off = ((c & 1) << 5) + (q << 3);
                const bf16* b = (seg == 0) ? A0 + (long)sidx[et]*64
                              : (seg == 1) ? A0 + (long)ridx[et]*64
                                           : A1 + (long)eclamp[et]*64;
                v = *(const bf16x8s*)(b + off);
            } else { // M_HMSG
                int seg = c >> 1; int off = ((c & 1) << 5) + (q << 3);
                const bf16* b = (seg == 0) ? A0 + (long)sidx[et]*64
                              : (seg == 1) ? A1 + (long)sidx[et]*64
                              : (seg == 2) ? A0 + (long)ridx[et]*64
                              : (seg == 3) ? A1 + (long)ridx[et]*64
                                           : A2 + (long)eclamp[et]*64;
                v = *(const bf16x8s*)(b + off);
            }
            af[et] = v;
        }
        #pragma unroll
        for (int t = 0; t < 4; ++t) {
            bf16x8s bfv = *(const bf16x8s*)(lds_w + ((long)(c*4 + t)*64 + lane)*8);
            #pragma unroll
            for (int et = 0; et < 4; ++et)
                acc[et][t] = __builtin_amdgcn_mfma_f32_16x16x32_bf16(af[et], bfv, acc[et][t], 0, 0, 0);
        }
    }

    // D layout: row = q*4 + reg, col = t*16 + l15
    #pragma unroll
    for (int et = 0; et < 4; ++et) {
        #pragma unroll
        for (int r = 0; r < 4; ++r) {
            long row = row_base + et*16 + q*4 + r;
            if (row < n_rows) {
                #pragma unroll
                for (int t = 0; t < 4; ++t) {
                    float fv = acc[et][t][r];
                    out[row*64 + t*16 + l15] = __float2bfloat16(fv);
                    if (out2) out2[row*64 + t*16 + l15] = fv;
                }
            }
        }
    }
}

// ======================= launch =======================
extern "C" void kernel_launch(void* const* d_in, const int* in_sizes, int n_in,
                              void* d_out, int out_size, void* d_ws, size_t ws_size,
                              hipStream_t stream)
{
    (void)in_sizes; (void)n_in; (void)out_size; (void)ws_size;
    const float* h_in = (const float*)d_in[0];
    const float* e_in = (const float*)d_in[1];
    const float* p_in = (const float*)d_in[2];
    const int*  ei   = (const int*)d_in[3];
    const int* send = ei;
    const int* rec  = ei + NE;
    const float* he_W = (const float*)d_in[4];  const float* he_b = (const float*)d_in[5];
    const float* ee_W = (const float*)d_in[6];  const float* ee_b = (const float*)d_in[7];
    const float* pe_W = (const float*)d_in[8];  const float* pe_b = (const float*)d_in[9];
    const float* hm_W = (const float*)d_in[10]; const float* hm_b = (const float*)d_in[11];
    const float* hu_W = (const float*)d_in[12]; const float* hu_b = (const float*)d_in[13];
    const float* eu_W = (const float*)d_in[14]; const float* eu_b = (const float*)d_in[15];
    const float* pm_W = (const float*)d_in[16]; const float* pm_b = (const float*)d_in[17];
    const float* pu_W = (const float*)d_in[18]; const float* pu_b = (const float*)d_in[19];

    char* ws = (char*)d_ws;
    bf16* e_buf = (bf16*)(ws + OFF_E);
    bf16* msg   = (bf16*)(ws + OFF_MSG);
    bf16* cvt_h = (bf16*)(ws + OFF_CVT_H);
    bf16* cvt_e = (bf16*)(ws + OFF_CVT_E);
    bf16* cvt_p = (bf16*)(ws + OFF_CVT_P);
    bf16* h     = (bf16*)(ws + OFF_H);
    bf16* p     = (bf16*)(ws + OFF_P);
    bf16* hagg  = (bf16*)(ws + OFF_HAGG);
    bf16* pagg  = (bf16*)(ws + OFF_PAGG);
    bf16* wf    = (bf16*)(ws + OFF_WFMT);
    int* rowptr = (int*)(ws + OFF_ROWPTR);
    int* colidx = (int*)(ws + OFF_COLIDX);
    int* cnt    = (int*)(ws + OFF_CNT);
    float* dout = (float*)d_out;

    const int EB = NE / 256;          // 3125 blocks, exact
    const int NB = (NN + 255) / 256;  // 196 blocks

    // CSR build (by rec): colidx[j] = original edge id at sorted position j
    hipMemsetAsync(cnt, 0, NN * sizeof(int), stream);
    hist_k<<<EB, 256, 0, stream>>>(rec, cnt);
    scan_k<<<1, 1024, 0, stream>>>(cnt, rowptr);
    hipMemsetAsync(cnt, 0, NN * sizeof(int), stream);
    scatter_k<<<EB, 256, 0, stream>>>(rec, rowptr, cnt, colidx);

    // input conversion fp32 -> bf16 (into the msg region; dead until the layer loop)
    cvt_k<<<(NN*128/4 + 255)/256, 256, 0, stream>>>(h_in, cvt_h, NN*128/4);
    cvt_k<<<(NE*16/4 + 255)/256, 256, 0, stream>>>(e_in, cvt_e, NE*16/4);
    cvt_k<<<(NN*16/4 + 255)/256, 256, 0, stream>>>(p_in, cvt_p, NN*16/4);

    // weight formatting
    wfmt_k<<<23, 256, 0, stream>>>(he_W, ee_W, pe_W, hm_W, hu_W, eu_W, pm_W, pu_W, wf);

    // embeddings (e lands directly in SORTED edge order via colidx gather)
    gemm_k<M_EMB128, 4><<<NB, 256, 0, stream>>>(cvt_h, nullptr, nullptr, nullptr, nullptr, nullptr,
        wf + WOFF_HE, he_b, h, nullptr, NN);
    gemm_k<M_EMB16G, 1><<<EB, 256, 0, stream>>>(cvt_e, nullptr, nullptr, nullptr, nullptr, colidx,
        wf + WOFF_EE, ee_b, e_buf, nullptr, NE);
    gemm_k<M_EMB16, 1><<<NB, 256, 0, stream>>>(cvt_p, nullptr, nullptr, nullptr, nullptr, nullptr,
        wf + WOFF_PE, pe_b, p, nullptr, NN);

    for (int i = 0; i < 4; ++i) {
        // h_msg[j] = [h[s],p[s],h[r],p[r],e[j]] @ hm_W[i]   (sorted order)
        gemm_k<M_HMSG, 10><<<EB, 256, 0, stream>>>(h, p, e_buf, send, rec, colidx,
            wf + WOFF_HM + (long)i*20480, hm_b + i*64, msg, nullptr, NE);
        agg_k<<<NN/4, 256, 0, stream>>>(msg, rowptr, hagg);
        // h = [h, h_agg] @ hu_W[i]
        gemm_k<M_NODE2, 4><<<NB, 256, 0, stream>>>(h, hagg, nullptr, nullptr, nullptr, nullptr,
            wf + WOFF_HU + (long)i*8192, hu_b + i*64, h, (i == 3) ? dout : nullptr, NN);
        // e[j] = [h[s], h[r], e[j]] @ eu_W[i]   (in-place per-row safe)
        gemm_k<M_EDGE3, 6><<<EB, 256, 0, stream>>>(h, e_buf, nullptr, send, rec, colidx,
            wf + WOFF_EU + (long)i*12288, eu_b + i*64, e_buf, nullptr, NE);
        // p_msg[j] = [p[s], p[r], e_new[j]] @ pm_W[i]
        gemm_k<M_EDGE3, 6><<<EB, 256, 0, stream>>>(p, e_buf, nullptr, send, rec, colidx,
            wf + WOFF_PM + (long)i*12288, pm_b + i*64, msg, nullptr, NE);
        agg_k<<<NN/4, 256, 0, stream>>>(msg, rowptr, pagg);
        // p = [p, p_agg] @ pu_W[i]
        gemm_k<M_NODE2, 4><<<NB, 256, 0, stream>>>(p, pagg, nullptr, nullptr, nullptr, nullptr,
            wf + WOFF_PU + (long)i*8192, pu_b + i*64, p, (i == 3) ? dout + (long)NN*64 : nullptr, NN);
    }
}

// Round 5
// 1607.095 us; speedup vs baseline: 1.2147x; 1.1364x over previous
//
#include <hip/hip_runtime.h>
#include <hip/hip_bf16.h>

#define NN 50000
#define NE 800000

typedef __hip_bfloat16 bf16;
typedef __attribute__((ext_vector_type(8))) short bf16x8s;   // 8 bf16 = 4 VGPRs
typedef __attribute__((ext_vector_type(4))) float f32x4;

// ---- workspace layout (bytes) ----
#define OFF_E      0L            // e buffer (SORTED edge order) [NE,64] bf16
// old msg region 102.4M..204.8M now hosts cvt inputs + seg + fp32 aggregates
#define OFF_CVT_H  102400000L    //   h_in bf16 [NN,128]
#define OFF_CVT_E  115200000L    //   e_in bf16 [NE,16]
#define OFF_CVT_P  140800000L    //   p_in bf16 [NN,16]
#define OFF_SEG    147400000L    //   seg[j] = rec of sorted edge j, NE int
#define OFF_HAGGF  160000000L    //   h_agg fp32 [NN,64] = 12.8 MB
#define OFF_PAGGF  172800000L    //   p_agg fp32 [NN,64] = 12.8 MB
#define OFF_H      204800000L    // h  [NN,64] bf16
#define OFF_P      211200000L    // p
#define OFF_WFMT   230400000L    // formatted weights, 258048 bf16
#define OFF_ROWPTR 230916096L    // (NN+1) int
#define OFF_COLIDX 231116104L    // NE int  (sorted-pos j -> original edge id)
#define OFF_CNT    234316104L    // NN int

// ---- formatted-weight element offsets ----
#define WOFF_HE 0
#define WOFF_EE 8192
#define WOFF_PE 10240
#define WOFF_HM 12288       // 4 x 20480
#define WOFF_HU 94208       // 4 x 8192
#define WOFF_EU 126976      // 4 x 12288
#define WOFF_PM 176128      // 4 x 12288
#define WOFF_PU 225280      // 4 x 8192

// gather modes
#define M_EMB16  0   // A0 rows of 16 (K=16 zero-padded to 32), direct rows
#define M_EMB128 1   // A0 rows of 128, direct rows
#define M_NODE2  2   // [A0[row], A1[row]] K=128 (A1 may be fp32 aggregate)
#define M_EDGE3  3   // [A0[s], A0[r], A1[j]] K=192, s/r via gmap indirection
#define M_HMSG   4   // [A0[s],A1[s],A0[r],A1[r],A2[j]] K=320
#define M_EMB16G 5   // A0 rows of 16 gathered via gmap (sorted e embedding)

// ======================= fp32 -> bf16 conversion =======================
__global__ __launch_bounds__(256) void cvt_k(const float* __restrict__ src,
                                             bf16* __restrict__ dst, int n4)
{
    int i = blockIdx.x*256 + threadIdx.x;
    if (i < n4) {
        float4 v = ((const float4*)src)[i];
        dst[i*4+0] = __float2bfloat16(v.x);
        dst[i*4+1] = __float2bfloat16(v.y);
        dst[i*4+2] = __float2bfloat16(v.z);
        dst[i*4+3] = __float2bfloat16(v.w);
    }
}

// ======================= weight formatting (fp32 -> bf16 B-fragments) ==
// Bfmt[((c*4+t)*64 + lane)*8 + j] = W[c*32 + (lane>>4)*8 + j][t*16 + (lane&15)]
__global__ __launch_bounds__(256) void wfmt_k(
    const float* __restrict__ he, const float* __restrict__ ee, const float* __restrict__ pe,
    const float* __restrict__ hm, const float* __restrict__ hu, const float* __restrict__ eu,
    const float* __restrict__ pm, const float* __restrict__ pu, bf16* __restrict__ wf)
{
    int s = blockIdx.x;
    const float* src; int Ksrc, Kpad; long doff;
    if      (s == 0) { src = he; Ksrc = 128; Kpad = 128; doff = WOFF_HE; }
    else if (s == 1) { src = ee; Ksrc = 16;  Kpad = 32;  doff = WOFF_EE; }
    else if (s == 2) { src = pe; Ksrc = 16;  Kpad = 32;  doff = WOFF_PE; }
    else if (s < 7)  { int i = s - 3;  src = hm + (long)i*320*64; Ksrc = 320; Kpad = 320; doff = WOFF_HM + (long)i*20480; }
    else if (s < 11) { int i = s - 7;  src = hu + (long)i*128*64; Ksrc = 128; Kpad = 128; doff = WOFF_HU + (long)i*8192; }
    else if (s < 15) { int i = s - 11; src = eu + (long)i*192*64; Ksrc = 192; Kpad = 192; doff = WOFF_EU + (long)i*12288; }
    else if (s < 19) { int i = s - 15; src = pm + (long)i*192*64; Ksrc = 192; Kpad = 192; doff = WOFF_PM + (long)i*12288; }
    else             { int i = s - 19; src = pu + (long)i*128*64; Ksrc = 128; Kpad = 128; doff = WOFF_PU + (long)i*8192; }
    int total = Kpad * 64;
    for (int idx = threadIdx.x; idx < total; idx += blockDim.x) {
        int j = idx & 7, l = (idx >> 3) & 63, ct = idx >> 9;
        int c = ct >> 2, t = ct & 3;
        int k = c*32 + (l >> 4)*8 + j;
        int n = t*16 + (l & 15);
        wf[doff + idx] = (k < Ksrc) ? __float2bfloat16(src[(long)k*64 + n])
                                    : __float2bfloat16(0.0f);
    }
}

// ======================= CSR build =======================
__global__ __launch_bounds__(256) void hist_k(const int* __restrict__ rec, int* __restrict__ cnt)
{
    int e = blockIdx.x*256 + threadIdx.x;
    if (e < NE) atomicAdd(&cnt[rec[e]], 1);
}

__global__ __launch_bounds__(1024) void scan_k(const int* __restrict__ cnt, int* __restrict__ rowptr)
{
    __shared__ int sdata[1024];
    __shared__ int s_carry;
    int tid = threadIdx.x;
    if (tid == 0) { s_carry = 0; rowptr[0] = 0; }
    __syncthreads();
    for (int base = 0; base < NN; base += 1024) {
        int i = base + tid;
        int v = (i < NN) ? cnt[i] : 0;
        sdata[tid] = v;
        __syncthreads();
        for (int off = 1; off < 1024; off <<= 1) {
            int t = (tid >= off) ? sdata[tid - off] : 0;
            __syncthreads();
            sdata[tid] += t;
            __syncthreads();
        }
        int total = sdata[1023];
        if (i < NN) rowptr[i + 1] = s_carry + sdata[tid];
        __syncthreads();
        if (tid == 0) s_carry += total;
        __syncthreads();
    }
}

__global__ __launch_bounds__(256) void scatter_k(const int* __restrict__ rec,
    const int* __restrict__ rowptr, int* __restrict__ cursor,
    int* __restrict__ colidx, int* __restrict__ seg)
{
    int e = blockIdx.x*256 + threadIdx.x;
    if (e < NE) {
        int r = rec[e];
        int pos = atomicAdd(&cursor[r], 1);
        colidx[rowptr[r] + pos] = e;
        seg[rowptr[r] + pos] = r;
    }
}

// ======================= fused gather + GEMM (+ fused segment-sum) =======
// Per block: 256 rows. Per wave: 64 rows = 4 M-tiles of 16. N=64 = 4 tiles.
// Edge modes operate on SORTED edge positions j; original edge id = gmap[j].
// AGG: instead of storing D rows, segment-sum them per rec-node (edges are
// rec-sorted, so a block spans ~17 consecutive nodes) and atomicAdd fp32.
template <int MODE, int KCH, bool AGG, bool A1F32>
__global__ __launch_bounds__(256) void gemm_k(
    const bf16* __restrict__ A0, const bf16* __restrict__ A1, const float* __restrict__ A1f,
    const bf16* __restrict__ A2,
    const int* __restrict__ send, const int* __restrict__ rec, const int* __restrict__ gmap,
    const int* __restrict__ seg, const int* __restrict__ rowptr,
    const bf16* __restrict__ wf, const float* __restrict__ bias,
    bf16* __restrict__ out, float* __restrict__ out2, float* __restrict__ aggout,
    int n_rows)
{
    constexpr int WB = KCH * 4096;                       // weight bytes
    constexpr int LDSB = AGG ? (WB > 65536 ? WB : 65536) : WB;
    __shared__ __align__(16) char lds_raw[LDSB];
    bf16* lds_w = (bf16*)lds_raw;
    int tid = threadIdx.x;
    {   // stage formatted weights to LDS
        const int4* src = (const int4*)wf;
        int4* dst = (int4*)lds_raw;
        #pragma unroll
        for (int i = tid; i < KCH*256; i += 256) dst[i] = src[i];
    }
    __syncthreads();

    int lane = tid & 63, wv = tid >> 6;
    int l15 = lane & 15, q = lane >> 4;
    long row_base = (long)blockIdx.x*256 + wv*64;

    int eclamp[4], sidx[4], ridx[4];
    #pragma unroll
    for (int et = 0; et < 4; ++et) {
        long r = row_base + et*16 + l15;
        int rc = (r < n_rows) ? (int)r : (n_rows - 1);
        eclamp[et] = rc;
        if constexpr (MODE == M_EDGE3 || MODE == M_HMSG) {
            int em = gmap[rc];
            sidx[et] = send[em]; ridx[et] = rec[em];
        } else if constexpr (MODE == M_EMB16G) {
            sidx[et] = gmap[rc];
        }
    }

    float bv[4];
    #pragma unroll
    for (int t = 0; t < 4; ++t) bv[t] = bias[t*16 + l15];

    f32x4 acc[4][4];
    #pragma unroll
    for (int et = 0; et < 4; ++et)
        #pragma unroll
        for (int t = 0; t < 4; ++t) {
            acc[et][t][0] = bv[t]; acc[et][t][1] = bv[t];
            acc[et][t][2] = bv[t]; acc[et][t][3] = bv[t];
        }

    #pragma unroll
    for (int c = 0; c < KCH; ++c) {
        bf16x8s af[4];
        #pragma unroll
        for (int et = 0; et < 4; ++et) {
            bf16x8s v = {0,0,0,0,0,0,0,0};
            if constexpr (MODE == M_EMB16) {
                if (q < 2) v = *(const bf16x8s*)(A0 + (long)eclamp[et]*16 + q*8);
            } else if constexpr (MODE == M_EMB16G) {
                if (q < 2) v = *(const bf16x8s*)(A0 + (long)sidx[et]*16 + q*8);
            } else if constexpr (MODE == M_EMB128) {
                v = *(const bf16x8s*)(A0 + (long)eclamp[et]*128 + c*32 + q*8);
            } else if constexpr (MODE == M_NODE2) {
                int sgi = c >> 1; int off = ((c & 1) << 5) + (q << 3);
                if (sgi == 0) {
                    v = *(const bf16x8s*)(A0 + (long)eclamp[et]*64 + off);
                } else if constexpr (A1F32) {
                    const float* fp = A1f + (long)eclamp[et]*64 + off;
                    float4 f0 = ((const float4*)fp)[0];
                    float4 f1 = ((const float4*)fp)[1];
                    bf16 tmp[8];
                    tmp[0]=__float2bfloat16(f0.x); tmp[1]=__float2bfloat16(f0.y);
                    tmp[2]=__float2bfloat16(f0.z); tmp[3]=__float2bfloat16(f0.w);
                    tmp[4]=__float2bfloat16(f1.x); tmp[5]=__float2bfloat16(f1.y);
                    tmp[6]=__float2bfloat16(f1.z); tmp[7]=__float2bfloat16(f1.w);
                    v = *(const bf16x8s*)tmp;
                } else {
                    v = *(const bf16x8s*)(A1 + (long)eclamp[et]*64 + off);
                }
            } else if constexpr (MODE == M_EDGE3) {
                int sgi = c >> 1; int off = ((c & 1) << 5) + (q << 3);
                if (sgi == 2) {
                    v = __builtin_nontemporal_load((const bf16x8s*)(A1 + (long)eclamp[et]*64 + off));
                } else {
                    const bf16* b = (sgi == 0) ? A0 + (long)sidx[et]*64
                                               : A0 + (long)ridx[et]*64;
                    v = *(const bf16x8s*)(b + off);
                }
            } else { // M_HMSG
                int sgi = c >> 1; int off = ((c & 1) << 5) + (q << 3);
                if (sgi == 4) {
                    v = __builtin_nontemporal_load((const bf16x8s*)(A2 + (long)eclamp[et]*64 + off));
                } else {
                    const bf16* b = (sgi == 0) ? A0 + (long)sidx[et]*64
                                  : (sgi == 1) ? A1 + (long)sidx[et]*64
                                  : (sgi == 2) ? A0 + (long)ridx[et]*64
                                               : A1 + (long)ridx[et]*64;
                    v = *(const bf16x8s*)(b + off);
                }
            }
            af[et] = v;
        }
        #pragma unroll
        for (int t = 0; t < 4; ++t) {
            bf16x8s bfv = *(const bf16x8s*)(lds_w + ((long)(c*4 + t)*64 + lane)*8);
            #pragma unroll
            for (int et = 0; et < 4; ++et)
                acc[et][t] = __builtin_amdgcn_mfma_f32_16x16x32_bf16(af[et], bfv, acc[et][t], 0, 0, 0);
        }
    }

    if constexpr (AGG) {
        // ---- fused segment-sum epilogue (edges rec-sorted; NE % 256 == 0) ----
        __syncthreads();                      // everyone done reading lds_w
        float* sD = (float*)lds_raw;          // 256 x 64 fp32 = 64 KB (aliases lds_w)
        #pragma unroll
        for (int et = 0; et < 4; ++et)
            #pragma unroll
            for (int r = 0; r < 4; ++r)
                #pragma unroll
                for (int t = 0; t < 4; ++t)
                    sD[(wv*64 + et*16 + q*4 + r)*64 + t*16 + l15] = acc[et][t][r];
        __syncthreads();
        int col = tid & 63, wpart = tid >> 6;
        int gbase = blockIdx.x*256;
        int n0 = seg[gbase], n1 = seg[gbase + 255];
        for (int n = n0 + wpart; n <= n1; n += 4) {
            int beg = rowptr[n], end = rowptr[n + 1];
            if (beg < gbase) beg = gbase;
            if (end > gbase + 256) end = gbase + 256;
            if (beg < end) {
                float s = 0.0f;
                for (int j = beg; j < end; ++j) s += sD[(j - gbase)*64 + col];
                atomicAdd(&aggout[(long)n*64 + col], s);
            }
        }
    } else {
        // D layout: row = q*4 + reg, col = t*16 + l15
        #pragma unroll
        for (int et = 0; et < 4; ++et) {
            #pragma unroll
            for (int r = 0; r < 4; ++r) {
                long row = row_base + et*16 + q*4 + r;
                if (row < n_rows) {
                    #pragma unroll
                    for (int t = 0; t < 4; ++t) {
                        float fv = acc[et][t][r];
                        bf16 bvv = __float2bfloat16(fv);
                        if constexpr (MODE == M_EDGE3) {  // EU: e stream, non-temporal
                            __builtin_nontemporal_store(*(const short*)&bvv,
                                (short*)&out[row*64 + t*16 + l15]);
                        } else {
                            out[row*64 + t*16 + l15] = bvv;
                        }
                        if (out2) out2[row*64 + t*16 + l15] = fv;
                    }
                }
            }
        }
    }
}

// ======================= launch =======================
extern "C" void kernel_launch(void* const* d_in, const int* in_sizes, int n_in,
                              void* d_out, int out_size, void* d_ws, size_t ws_size,
                              hipStream_t stream)
{
    (void)in_sizes; (void)n_in; (void)out_size; (void)ws_size;
    const float* h_in = (const float*)d_in[0];
    const float* e_in = (const float*)d_in[1];
    const float* p_in = (const float*)d_in[2];
    const int*  ei   = (const int*)d_in[3];
    const int* send = ei;
    const int* rec  = ei + NE;
    const float* he_W = (const float*)d_in[4];  const float* he_b = (const float*)d_in[5];
    const float* ee_W = (const float*)d_in[6];  const float* ee_b = (const float*)d_in[7];
    const float* pe_W = (const float*)d_in[8];  const float* pe_b = (const float*)d_in[9];
    const float* hm_W = (const float*)d_in[10]; const float* hm_b = (const float*)d_in[11];
    const float* hu_W = (const float*)d_in[12]; const float* hu_b = (const float*)d_in[13];
    const float* eu_W = (const float*)d_in[14]; const float* eu_b = (const float*)d_in[15];
    const float* pm_W = (const float*)d_in[16]; const float* pm_b = (const float*)d_in[17];
    const float* pu_W = (const float*)d_in[18]; const float* pu_b = (const float*)d_in[19];

    char* ws = (char*)d_ws;
    bf16* e_buf = (bf16*)(ws + OFF_E);
    bf16* cvt_h = (bf16*)(ws + OFF_CVT_H);
    bf16* cvt_e = (bf16*)(ws + OFF_CVT_E);
    bf16* cvt_p = (bf16*)(ws + OFF_CVT_P);
    int*  segarr= (int*)(ws + OFF_SEG);
    float* haggf= (float*)(ws + OFF_HAGGF);
    float* paggf= (float*)(ws + OFF_PAGGF);
    bf16* h     = (bf16*)(ws + OFF_H);
    bf16* p     = (bf16*)(ws + OFF_P);
    bf16* wf    = (bf16*)(ws + OFF_WFMT);
    int* rowptr = (int*)(ws + OFF_ROWPTR);
    int* colidx = (int*)(ws + OFF_COLIDX);
    int* cnt    = (int*)(ws + OFF_CNT);
    float* dout = (float*)d_out;

    const int EB = NE / 256;          // 3125 blocks, exact
    const int NB = (NN + 255) / 256;  // 196 blocks

    // CSR build (by rec): colidx[j] = original edge id, seg[j] = rec node
    (void)hipMemsetAsync(cnt, 0, NN * sizeof(int), stream);
    hist_k<<<EB, 256, 0, stream>>>(rec, cnt);
    scan_k<<<1, 1024, 0, stream>>>(cnt, rowptr);
    (void)hipMemsetAsync(cnt, 0, NN * sizeof(int), stream);
    scatter_k<<<EB, 256, 0, stream>>>(rec, rowptr, cnt, colidx, segarr);

    // input conversion fp32 -> bf16
    cvt_k<<<(NN*128/4 + 255)/256, 256, 0, stream>>>(h_in, cvt_h, NN*128/4);
    cvt_k<<<(NE*16/4 + 255)/256, 256, 0, stream>>>(e_in, cvt_e, NE*16/4);
    cvt_k<<<(NN*16/4 + 255)/256, 256, 0, stream>>>(p_in, cvt_p, NN*16/4);

    // weight formatting
    wfmt_k<<<23, 256, 0, stream>>>(he_W, ee_W, pe_W, hm_W, hu_W, eu_W, pm_W, pu_W, wf);

    // embeddings (e lands directly in SORTED edge order via colidx gather)
    gemm_k<M_EMB128, 4, false, false><<<NB, 256, 0, stream>>>(cvt_h, nullptr, nullptr, nullptr,
        nullptr, nullptr, nullptr, nullptr, nullptr, wf + WOFF_HE, he_b, h, nullptr, nullptr, NN);
    gemm_k<M_EMB16G, 1, false, false><<<EB, 256, 0, stream>>>(cvt_e, nullptr, nullptr, nullptr,
        nullptr, nullptr, colidx, nullptr, nullptr, wf + WOFF_EE, ee_b, e_buf, nullptr, nullptr, NE);
    gemm_k<M_EMB16, 1, false, false><<<NB, 256, 0, stream>>>(cvt_p, nullptr, nullptr, nullptr,
        nullptr, nullptr, nullptr, nullptr, nullptr, wf + WOFF_PE, pe_b, p, nullptr, nullptr, NN);

    for (int i = 0; i < 4; ++i) {
        // h_agg = segment_sum([h[s],p[s],h[r],p[r],e] @ hm_W[i])  — fused
        (void)hipMemsetAsync(haggf, 0, (long)NN*64*sizeof(float), stream);
        gemm_k<M_HMSG, 10, true, false><<<EB, 256, 0, stream>>>(h, p, nullptr, e_buf,
            send, rec, colidx, segarr, rowptr,
            wf + WOFF_HM + (long)i*20480, hm_b + i*64, nullptr, nullptr, haggf, NE);
        // h = [h, h_agg] @ hu_W[i]   (A1 = fp32 aggregate)
        gemm_k<M_NODE2, 4, false, true><<<NB, 256, 0, stream>>>(h, nullptr, haggf, nullptr,
            nullptr, nullptr, nullptr, nullptr, nullptr,
            wf + WOFF_HU + (long)i*8192, hu_b + i*64, h, (i == 3) ? dout : nullptr, nullptr, NN);
        // e[j] = [h[s], h[r], e[j]] @ eu_W[i]   (in-place per-row safe, NT stream)
        gemm_k<M_EDGE3, 6, false, false><<<EB, 256, 0, stream>>>(h, e_buf, nullptr, nullptr,
            send, rec, colidx, nullptr, nullptr,
            wf + WOFF_EU + (long)i*12288, eu_b + i*64, e_buf, nullptr, nullptr, NE);
        // p_agg = segment_sum([p[s], p[r], e_new] @ pm_W[i])  — fused
        (void)hipMemsetAsync(paggf, 0, (long)NN*64*sizeof(float), stream);
        gemm_k<M_EDGE3, 6, true, false><<<EB, 256, 0, stream>>>(p, e_buf, nullptr, nullptr,
            send, rec, colidx, segarr, rowptr,
            wf + WOFF_PM + (long)i*12288, pm_b + i*64, nullptr, nullptr, paggf, NE);
        // p = [p, p_agg] @ pu_W[i]
        gemm_k<M_NODE2, 4, false, true><<<NB, 256, 0, stream>>>(p, nullptr, paggf, nullptr,
            nullptr, nullptr, nullptr, nullptr, nullptr,
            wf + WOFF_PU + (long)i*8192, pu_b + i*64, p, (i == 3) ? dout + (long)NN*64 : nullptr, nullptr, NN);
    }
}

// Round 6
// 1529.265 us; speedup vs baseline: 1.2765x; 1.0509x over previous
//
#include <hip/hip_runtime.h>
#include <hip/hip_bf16.h>

#define NN 50000
#define NE 800000

typedef __hip_bfloat16 bf16;
typedef __attribute__((ext_vector_type(8))) short bf16x8s;   // 8 bf16 = 4 VGPRs
typedef __attribute__((ext_vector_type(4))) float f32x4;

// ---- workspace layout (bytes) ----
#define OFF_E      0L            // e buffer (SORTED edge order) [NE,64] bf16
#define OFF_CVT_H  102400000L    //   h_in bf16 [NN,128]
#define OFF_CVT_E  115200000L    //   e_in bf16 [NE,16]
#define OFF_CVT_P  140800000L    //   p_in bf16 [NN,16]
#define OFF_SEG    147400000L    //   seg[j] = rec of sorted edge j, NE int
#define OFF_HAGGF  160000000L    //   h_agg fp32 [NN,64] = 12.8 MB
#define OFF_PAGGF  172800000L    //   p_agg fp32 [NN,64] = 12.8 MB
#define OFF_H      204800000L    // h  [NN,64] bf16
#define OFF_P      211200000L    // p
#define OFF_WFMT   230400000L    // formatted weights, 258048 bf16
#define OFF_ROWPTR 230916096L    // (NN+1) int
#define OFF_COLIDX 231116104L    // NE int  (sorted-pos j -> original edge id)
#define OFF_CNT    234316104L    // NN int

// ---- formatted-weight element offsets ----
#define WOFF_HE 0
#define WOFF_EE 8192
#define WOFF_PE 10240
#define WOFF_HM 12288       // 4 x 20480
#define WOFF_HU 94208       // 4 x 8192
#define WOFF_EU 126976      // 4 x 12288
#define WOFF_PM 176128      // 4 x 12288
#define WOFF_PU 225280      // 4 x 8192

// gather modes
#define M_EMB16  0
#define M_EMB128 1
#define M_NODE2  2
#define M_EDGE3  3
#define M_HMSG   4
#define M_EMB16G 5

// agg staging tile: 256 rows x stride 72 bf16 (pad 64->72 kills bank conflicts:
// 4-row q-shift = 144 dwords = 16 mod 32 -> 2-way aliasing only, free)
#define AGG_STRIDE 72
#define AGG_BYTES  (256 * AGG_STRIDE * 2)   // 36864

// ======================= fp32 -> bf16 conversion =======================
__global__ __launch_bounds__(256) void cvt_k(const float* __restrict__ src,
                                             bf16* __restrict__ dst, int n4)
{
    int i = blockIdx.x*256 + threadIdx.x;
    if (i < n4) {
        float4 v = ((const float4*)src)[i];
        dst[i*4+0] = __float2bfloat16(v.x);
        dst[i*4+1] = __float2bfloat16(v.y);
        dst[i*4+2] = __float2bfloat16(v.z);
        dst[i*4+3] = __float2bfloat16(v.w);
    }
}

// ======================= weight formatting (fp32 -> bf16 B-fragments) ==
__global__ __launch_bounds__(256) void wfmt_k(
    const float* __restrict__ he, const float* __restrict__ ee, const float* __restrict__ pe,
    const float* __restrict__ hm, const float* __restrict__ hu, const float* __restrict__ eu,
    const float* __restrict__ pm, const float* __restrict__ pu, bf16* __restrict__ wf)
{
    int s = blockIdx.x;
    const float* src; int Ksrc, Kpad; long doff;
    if      (s == 0) { src = he; Ksrc = 128; Kpad = 128; doff = WOFF_HE; }
    else if (s == 1) { src = ee; Ksrc = 16;  Kpad = 32;  doff = WOFF_EE; }
    else if (s == 2) { src = pe; Ksrc = 16;  Kpad = 32;  doff = WOFF_PE; }
    else if (s < 7)  { int i = s - 3;  src = hm + (long)i*320*64; Ksrc = 320; Kpad = 320; doff = WOFF_HM + (long)i*20480; }
    else if (s < 11) { int i = s - 7;  src = hu + (long)i*128*64; Ksrc = 128; Kpad = 128; doff = WOFF_HU + (long)i*8192; }
    else if (s < 15) { int i = s - 11; src = eu + (long)i*192*64; Ksrc = 192; Kpad = 192; doff = WOFF_EU + (long)i*12288; }
    else if (s < 19) { int i = s - 15; src = pm + (long)i*192*64; Ksrc = 192; Kpad = 192; doff = WOFF_PM + (long)i*12288; }
    else             { int i = s - 19; src = pu + (long)i*128*64; Ksrc = 128; Kpad = 128; doff = WOFF_PU + (long)i*8192; }
    int total = Kpad * 64;
    for (int idx = threadIdx.x; idx < total; idx += blockDim.x) {
        int j = idx & 7, l = (idx >> 3) & 63, ct = idx >> 9;
        int c = ct >> 2, t = ct & 3;
        int k = c*32 + (l >> 4)*8 + j;
        int n = t*16 + (l & 15);
        wf[doff + idx] = (k < Ksrc) ? __float2bfloat16(src[(long)k*64 + n])
                                    : __float2bfloat16(0.0f);
    }
}

// ======================= CSR build =======================
__global__ __launch_bounds__(256) void hist_k(const int* __restrict__ rec, int* __restrict__ cnt)
{
    int e = blockIdx.x*256 + threadIdx.x;
    if (e < NE) atomicAdd(&cnt[rec[e]], 1);
}

__global__ __launch_bounds__(1024) void scan_k(const int* __restrict__ cnt, int* __restrict__ rowptr)
{
    __shared__ int sdata[1024];
    __shared__ int s_carry;
    int tid = threadIdx.x;
    if (tid == 0) { s_carry = 0; rowptr[0] = 0; }
    __syncthreads();
    for (int base = 0; base < NN; base += 1024) {
        int i = base + tid;
        int v = (i < NN) ? cnt[i] : 0;
        sdata[tid] = v;
        __syncthreads();
        for (int off = 1; off < 1024; off <<= 1) {
            int t = (tid >= off) ? sdata[tid - off] : 0;
            __syncthreads();
            sdata[tid] += t;
            __syncthreads();
        }
        int total = sdata[1023];
        if (i < NN) rowptr[i + 1] = s_carry + sdata[tid];
        __syncthreads();
        if (tid == 0) s_carry += total;
        __syncthreads();
    }
}

__global__ __launch_bounds__(256) void scatter_k(const int* __restrict__ rec,
    const int* __restrict__ rowptr, int* __restrict__ cursor,
    int* __restrict__ colidx, int* __restrict__ seg)
{
    int e = blockIdx.x*256 + threadIdx.x;
    if (e < NE) {
        int r = rec[e];
        int pos = atomicAdd(&cursor[r], 1);
        colidx[rowptr[r] + pos] = e;
        seg[rowptr[r] + pos] = r;
    }
}

// ======================= fused gather + GEMM (+ fused segment-sum) =======
template <int MODE, int KCH, bool AGG, bool A1F32>
__global__ __launch_bounds__(256) void gemm_k(
    const bf16* __restrict__ A0, const bf16* __restrict__ A1, const float* __restrict__ A1f,
    const bf16* __restrict__ A2,
    const int* __restrict__ send, const int* __restrict__ rec, const int* __restrict__ gmap,
    const int* __restrict__ seg, const int* __restrict__ rowptr,
    const bf16* __restrict__ wf, const float* __restrict__ bias,
    bf16* __restrict__ out, float* __restrict__ out2, float* __restrict__ aggout,
    int n_rows)
{
    constexpr int WB = KCH * 4096;                       // weight bytes
    constexpr int LDSB = AGG ? (WB > AGG_BYTES ? WB : AGG_BYTES) : WB;
    __shared__ __align__(16) char lds_raw[LDSB];
    bf16* lds_w = (bf16*)lds_raw;
    int tid = threadIdx.x;
    {   // stage formatted weights to LDS
        const int4* src = (const int4*)wf;
        int4* dst = (int4*)lds_raw;
        #pragma unroll
        for (int i = tid; i < KCH*256; i += 256) dst[i] = src[i];
    }
    __syncthreads();

    int lane = tid & 63, wv = tid >> 6;
    int l15 = lane & 15, q = lane >> 4;
    long row_base = (long)blockIdx.x*256 + wv*64;

    int eclamp[4], sidx[4], ridx[4];
    #pragma unroll
    for (int et = 0; et < 4; ++et) {
        long r = row_base + et*16 + l15;
        int rc = (r < n_rows) ? (int)r : (n_rows - 1);
        eclamp[et] = rc;
        if constexpr (MODE == M_EDGE3 || MODE == M_HMSG) {
            int em = gmap[rc];
            sidx[et] = send[em]; ridx[et] = rec[em];
        } else if constexpr (MODE == M_EMB16G) {
            sidx[et] = gmap[rc];
        }
    }

    float bv[4];
    #pragma unroll
    for (int t = 0; t < 4; ++t) bv[t] = bias[t*16 + l15];

    f32x4 acc[4][4];
    #pragma unroll
    for (int et = 0; et < 4; ++et)
        #pragma unroll
        for (int t = 0; t < 4; ++t) {
            acc[et][t][0] = bv[t]; acc[et][t][1] = bv[t];
            acc[et][t][2] = bv[t]; acc[et][t][3] = bv[t];
        }

    #pragma unroll
    for (int c = 0; c < KCH; ++c) {
        bf16x8s af[4];
        #pragma unroll
        for (int et = 0; et < 4; ++et) {
            bf16x8s v = {0,0,0,0,0,0,0,0};
            if constexpr (MODE == M_EMB16) {
                if (q < 2) v = *(const bf16x8s*)(A0 + (long)eclamp[et]*16 + q*8);
            } else if constexpr (MODE == M_EMB16G) {
                if (q < 2) v = *(const bf16x8s*)(A0 + (long)sidx[et]*16 + q*8);
            } else if constexpr (MODE == M_EMB128) {
                v = *(const bf16x8s*)(A0 + (long)eclamp[et]*128 + c*32 + q*8);
            } else if constexpr (MODE == M_NODE2) {
                int sgi = c >> 1; int off = ((c & 1) << 5) + (q << 3);
                if (sgi == 0) {
                    v = *(const bf16x8s*)(A0 + (long)eclamp[et]*64 + off);
                } else if constexpr (A1F32) {
                    const float* fp = A1f + (long)eclamp[et]*64 + off;
                    float4 f0 = ((const float4*)fp)[0];
                    float4 f1 = ((const float4*)fp)[1];
                    bf16 tmp[8];
                    tmp[0]=__float2bfloat16(f0.x); tmp[1]=__float2bfloat16(f0.y);
                    tmp[2]=__float2bfloat16(f0.z); tmp[3]=__float2bfloat16(f0.w);
                    tmp[4]=__float2bfloat16(f1.x); tmp[5]=__float2bfloat16(f1.y);
                    tmp[6]=__float2bfloat16(f1.z); tmp[7]=__float2bfloat16(f1.w);
                    v = *(const bf16x8s*)tmp;
                } else {
                    v = *(const bf16x8s*)(A1 + (long)eclamp[et]*64 + off);
                }
            } else if constexpr (MODE == M_EDGE3) {
                int sgi = c >> 1; int off = ((c & 1) << 5) + (q << 3);
                if (sgi == 2) {
                    v = __builtin_nontemporal_load((const bf16x8s*)(A1 + (long)eclamp[et]*64 + off));
                } else {
                    const bf16* b = (sgi == 0) ? A0 + (long)sidx[et]*64
                                               : A0 + (long)ridx[et]*64;
                    v = *(const bf16x8s*)(b + off);
                }
            } else { // M_HMSG
                int sgi = c >> 1; int off = ((c & 1) << 5) + (q << 3);
                if (sgi == 4) {
                    v = __builtin_nontemporal_load((const bf16x8s*)(A2 + (long)eclamp[et]*64 + off));
                } else {
                    const bf16* b = (sgi == 0) ? A0 + (long)sidx[et]*64
                                  : (sgi == 1) ? A1 + (long)sidx[et]*64
                                  : (sgi == 2) ? A0 + (long)ridx[et]*64
                                               : A1 + (long)ridx[et]*64;
                    v = *(const bf16x8s*)(b + off);
                }
            }
            af[et] = v;
        }
        #pragma unroll
        for (int t = 0; t < 4; ++t) {
            bf16x8s bfv = *(const bf16x8s*)(lds_w + ((long)(c*4 + t)*64 + lane)*8);
            #pragma unroll
            for (int et = 0; et < 4; ++et)
                acc[et][t] = __builtin_amdgcn_mfma_f32_16x16x32_bf16(af[et], bfv, acc[et][t], 0, 0, 0);
        }
    }

    if constexpr (AGG) {
        // ---- fused segment-sum epilogue (edges rec-sorted; NE % 256 == 0) ----
        // bf16 staging tile with stride 72: fits under the weight buffer for
        // KCH>=9 (HMSG) and costs only 36.9 KB for PM -> 4 blocks/CU.
        __syncthreads();                      // everyone done reading lds_w
        bf16* sD = (bf16*)lds_raw;
        #pragma unroll
        for (int et = 0; et < 4; ++et)
            #pragma unroll
            for (int r = 0; r < 4; ++r)
                #pragma unroll
                for (int t = 0; t < 4; ++t)
                    sD[(wv*64 + et*16 + q*4 + r)*AGG_STRIDE + t*16 + l15] =
                        __float2bfloat16(acc[et][t][r]);
        __syncthreads();
        int col = tid & 63, wpart = tid >> 6;
        int gbase = blockIdx.x*256;
        int n0 = seg[gbase], n1 = seg[gbase + 255];
        for (int n = n0 + wpart; n <= n1; n += 4) {
            int beg = rowptr[n], end = rowptr[n + 1];
            if (beg < gbase) beg = gbase;
            if (end > gbase + 256) end = gbase + 256;
            if (beg < end) {
                float s = 0.0f;
                for (int j = beg; j < end; ++j)
                    s += __bfloat162float(sD[(j - gbase)*AGG_STRIDE + col]);
                atomicAdd(&aggout[(long)n*64 + col], s);
            }
        }
    } else {
        // D layout: row = q*4 + reg, col = t*16 + l15
        #pragma unroll
        for (int et = 0; et < 4; ++et) {
            #pragma unroll
            for (int r = 0; r < 4; ++r) {
                long row = row_base + et*16 + q*4 + r;
                if (row < n_rows) {
                    #pragma unroll
                    for (int t = 0; t < 4; ++t) {
                        float fv = acc[et][t][r];
                        bf16 bvv = __float2bfloat16(fv);
                        if constexpr (MODE == M_EDGE3) {  // EU: e stream, non-temporal
                            __builtin_nontemporal_store(*(const short*)&bvv,
                                (short*)&out[row*64 + t*16 + l15]);
                        } else {
                            out[row*64 + t*16 + l15] = bvv;
                        }
                        if (out2) out2[row*64 + t*16 + l15] = fv;
                    }
                }
            }
        }
    }
}

// ======================= launch =======================
extern "C" void kernel_launch(void* const* d_in, const int* in_sizes, int n_in,
                              void* d_out, int out_size, void* d_ws, size_t ws_size,
                              hipStream_t stream)
{
    (void)in_sizes; (void)n_in; (void)out_size; (void)ws_size;
    const float* h_in = (const float*)d_in[0];
    const float* e_in = (const float*)d_in[1];
    const float* p_in = (const float*)d_in[2];
    const int*  ei   = (const int*)d_in[3];
    const int* send = ei;
    const int* rec  = ei + NE;
    const float* he_W = (const float*)d_in[4];  const float* he_b = (const float*)d_in[5];
    const float* ee_W = (const float*)d_in[6];  const float* ee_b = (const float*)d_in[7];
    const float* pe_W = (const float*)d_in[8];  const float* pe_b = (const float*)d_in[9];
    const float* hm_W = (const float*)d_in[10]; const float* hm_b = (const float*)d_in[11];
    const float* hu_W = (const float*)d_in[12]; const float* hu_b = (const float*)d_in[13];
    const float* eu_W = (const float*)d_in[14]; const float* eu_b = (const float*)d_in[15];
    const float* pm_W = (const float*)d_in[16]; const float* pm_b = (const float*)d_in[17];
    const float* pu_W = (const float*)d_in[18]; const float* pu_b = (const float*)d_in[19];

    char* ws = (char*)d_ws;
    bf16* e_buf = (bf16*)(ws + OFF_E);
    bf16* cvt_h = (bf16*)(ws + OFF_CVT_H);
    bf16* cvt_e = (bf16*)(ws + OFF_CVT_E);
    bf16* cvt_p = (bf16*)(ws + OFF_CVT_P);
    int*  segarr= (int*)(ws + OFF_SEG);
    float* haggf= (float*)(ws + OFF_HAGGF);
    float* paggf= (float*)(ws + OFF_PAGGF);
    bf16* h     = (bf16*)(ws + OFF_H);
    bf16* p     = (bf16*)(ws + OFF_P);
    bf16* wf    = (bf16*)(ws + OFF_WFMT);
    int* rowptr = (int*)(ws + OFF_ROWPTR);
    int* colidx = (int*)(ws + OFF_COLIDX);
    int* cnt    = (int*)(ws + OFF_CNT);
    float* dout = (float*)d_out;

    const int EB = NE / 256;          // 3125 blocks, exact
    const int NB = (NN + 255) / 256;  // 196 blocks

    // CSR build (by rec): colidx[j] = original edge id, seg[j] = rec node
    (void)hipMemsetAsync(cnt, 0, NN * sizeof(int), stream);
    hist_k<<<EB, 256, 0, stream>>>(rec, cnt);
    scan_k<<<1, 1024, 0, stream>>>(cnt, rowptr);
    (void)hipMemsetAsync(cnt, 0, NN * sizeof(int), stream);
    scatter_k<<<EB, 256, 0, stream>>>(rec, rowptr, cnt, colidx, segarr);

    // input conversion fp32 -> bf16
    cvt_k<<<(NN*128/4 + 255)/256, 256, 0, stream>>>(h_in, cvt_h, NN*128/4);
    cvt_k<<<(NE*16/4 + 255)/256, 256, 0, stream>>>(e_in, cvt_e, NE*16/4);
    cvt_k<<<(NN*16/4 + 255)/256, 256, 0, stream>>>(p_in, cvt_p, NN*16/4);

    // weight formatting
    wfmt_k<<<23, 256, 0, stream>>>(he_W, ee_W, pe_W, hm_W, hu_W, eu_W, pm_W, pu_W, wf);

    // embeddings (e lands directly in SORTED edge order via colidx gather)
    gemm_k<M_EMB128, 4, false, false><<<NB, 256, 0, stream>>>(cvt_h, nullptr, nullptr, nullptr,
        nullptr, nullptr, nullptr, nullptr, nullptr, wf + WOFF_HE, he_b, h, nullptr, nullptr, NN);
    gemm_k<M_EMB16G, 1, false, false><<<EB, 256, 0, stream>>>(cvt_e, nullptr, nullptr, nullptr,
        nullptr, nullptr, colidx, nullptr, nullptr, wf + WOFF_EE, ee_b, e_buf, nullptr, nullptr, NE);
    gemm_k<M_EMB16, 1, false, false><<<NB, 256, 0, stream>>>(cvt_p, nullptr, nullptr, nullptr,
        nullptr, nullptr, nullptr, nullptr, nullptr, wf + WOFF_PE, pe_b, p, nullptr, nullptr, NN);

    for (int i = 0; i < 4; ++i) {
        // h_agg = segment_sum([h[s],p[s],h[r],p[r],e] @ hm_W[i])  — fused
        (void)hipMemsetAsync(haggf, 0, (long)NN*64*sizeof(float), stream);
        gemm_k<M_HMSG, 10, true, false><<<EB, 256, 0, stream>>>(h, p, nullptr, e_buf,
            send, rec, colidx, segarr, rowptr,
            wf + WOFF_HM + (long)i*20480, hm_b + i*64, nullptr, nullptr, haggf, NE);
        // h = [h, h_agg] @ hu_W[i]   (A1 = fp32 aggregate)
        gemm_k<M_NODE2, 4, false, true><<<NB, 256, 0, stream>>>(h, nullptr, haggf, nullptr,
            nullptr, nullptr, nullptr, nullptr, nullptr,
            wf + WOFF_HU + (long)i*8192, hu_b + i*64, h, (i == 3) ? dout : nullptr, nullptr, NN);
        // e[j] = [h[s], h[r], e[j]] @ eu_W[i]   (in-place per-row safe, NT stream)
        gemm_k<M_EDGE3, 6, false, false><<<EB, 256, 0, stream>>>(h, e_buf, nullptr, nullptr,
            send, rec, colidx, nullptr, nullptr,
            wf + WOFF_EU + (long)i*12288, eu_b + i*64, e_buf, nullptr, nullptr, NE);
        // p_agg = segment_sum([p[s], p[r], e_new] @ pm_W[i])  — fused
        (void)hipMemsetAsync(paggf, 0, (long)NN*64*sizeof(float), stream);
        gemm_k<M_EDGE3, 6, true, false><<<EB, 256, 0, stream>>>(p, e_buf, nullptr, nullptr,
            send, rec, colidx, segarr, rowptr,
            wf + WOFF_PM + (long)i*12288, pm_b + i*64, nullptr, nullptr, paggf, NE);
        // p = [p, p_agg] @ pu_W[i]
        gemm_k<M_NODE2, 4, false, true><<<NB, 256, 0, stream>>>(p, nullptr, paggf, nullptr,
            nullptr, nullptr, nullptr, nullptr, nullptr,
            wf + WOFF_PU + (long)i*8192, pu_b + i*64, p, (i == 3) ? dout + (long)NN*64 : nullptr, nullptr, NN);
    }
}

// Round 7
// 1474.115 us; speedup vs baseline: 1.3243x; 1.0374x over previous
//
#include <hip/hip_runtime.h>
#include <hip/hip_bf16.h>

#define NN 50000
#define NE 800000

typedef __hip_bfloat16 bf16;
typedef __attribute__((ext_vector_type(8))) short bf16x8s;   // 8 bf16 = 4 VGPRs
typedef __attribute__((ext_vector_type(4))) float f32x4;

// ---- workspace layout (bytes) ----
#define OFF_E      0L            // e buffer (SORTED edge order) [NE,64] bf16
#define OFF_CVT_H  102400000L    //   h_in bf16 [NN,128]
#define OFF_CVT_E  115200000L    //   e_in bf16 [NE,16]
#define OFF_CVT_P  140800000L    //   p_in bf16 [NN,16]
#define OFF_SEG    147400000L    //   seg[j] = rec of sorted edge j, NE int
#define OFF_HAGGF  160000000L    //   h_agg fp32 [NN,64] = 12.8 MB
#define OFF_PAGGF  172800000L    //   p_agg fp32 [NN,64] = 12.8 MB
#define OFF_H      204800000L    // h  [NN,64] bf16
#define OFF_P      211200000L    // p
#define OFF_WFMT   230400000L    // formatted weights, 258048 bf16 (L2-resident)
#define OFF_ROWPTR 230916096L    // (NN+1) int
#define OFF_COLIDX 231116104L    // NE int  (sorted-pos j -> original edge id)
#define OFF_CNT    234316104L    // NN int

// ---- formatted-weight element offsets ----
#define WOFF_HE 0
#define WOFF_EE 8192
#define WOFF_PE 10240
#define WOFF_HM 12288       // 4 x 20480
#define WOFF_HU 94208       // 4 x 8192
#define WOFF_EU 126976      // 4 x 12288
#define WOFF_PM 176128      // 4 x 12288
#define WOFF_PU 225280      // 4 x 8192

// gather modes
#define M_EMB16  0
#define M_EMB128 1
#define M_NODE2  2
#define M_HMSG   4
#define M_EMB16G 5

// agg / e_new staging tile: 256 rows x stride 72 bf16 (pad kills conflicts)
#define AGG_STRIDE 72
#define AGG_BYTES  (256 * AGG_STRIDE * 2)   // 36864

// ======================= fp32 -> bf16 conversion =======================
__global__ __launch_bounds__(256) void cvt_k(const float* __restrict__ src,
                                             bf16* __restrict__ dst, int n4)
{
    int i = blockIdx.x*256 + threadIdx.x;
    if (i < n4) {
        float4 v = ((const float4*)src)[i];
        dst[i*4+0] = __float2bfloat16(v.x);
        dst[i*4+1] = __float2bfloat16(v.y);
        dst[i*4+2] = __float2bfloat16(v.z);
        dst[i*4+3] = __float2bfloat16(v.w);
    }
}

// ======================= weight formatting (fp32 -> bf16 B-fragments) ==
__global__ __launch_bounds__(256) void wfmt_k(
    const float* __restrict__ he, const float* __restrict__ ee, const float* __restrict__ pe,
    const float* __restrict__ hm, const float* __restrict__ hu, const float* __restrict__ eu,
    const float* __restrict__ pm, const float* __restrict__ pu, bf16* __restrict__ wf)
{
    int s = blockIdx.x;
    const float* src; int Ksrc, Kpad; long doff;
    if      (s == 0) { src = he; Ksrc = 128; Kpad = 128; doff = WOFF_HE; }
    else if (s == 1) { src = ee; Ksrc = 16;  Kpad = 32;  doff = WOFF_EE; }
    else if (s == 2) { src = pe; Ksrc = 16;  Kpad = 32;  doff = WOFF_PE; }
    else if (s < 7)  { int i = s - 3;  src = hm + (long)i*320*64; Ksrc = 320; Kpad = 320; doff = WOFF_HM + (long)i*20480; }
    else if (s < 11) { int i = s - 7;  src = hu + (long)i*128*64; Ksrc = 128; Kpad = 128; doff = WOFF_HU + (long)i*8192; }
    else if (s < 15) { int i = s - 11; src = eu + (long)i*192*64; Ksrc = 192; Kpad = 192; doff = WOFF_EU + (long)i*12288; }
    else if (s < 19) { int i = s - 15; src = pm + (long)i*192*64; Ksrc = 192; Kpad = 192; doff = WOFF_PM + (long)i*12288; }
    else             { int i = s - 19; src = pu + (long)i*128*64; Ksrc = 128; Kpad = 128; doff = WOFF_PU + (long)i*8192; }
    int total = Kpad * 64;
    for (int idx = threadIdx.x; idx < total; idx += blockDim.x) {
        int j = idx & 7, l = (idx >> 3) & 63, ct = idx >> 9;
        int c = ct >> 2, t = ct & 3;
        int k = c*32 + (l >> 4)*8 + j;
        int n = t*16 + (l & 15);
        wf[doff + idx] = (k < Ksrc) ? __float2bfloat16(src[(long)k*64 + n])
                                    : __float2bfloat16(0.0f);
    }
}

// ======================= CSR build =======================
__global__ __launch_bounds__(256) void hist_k(const int* __restrict__ rec, int* __restrict__ cnt)
{
    int e = blockIdx.x*256 + threadIdx.x;
    if (e < NE) atomicAdd(&cnt[rec[e]], 1);
}

__global__ __launch_bounds__(1024) void scan_k(const int* __restrict__ cnt, int* __restrict__ rowptr)
{
    __shared__ int sdata[1024];
    __shared__ int s_carry;
    int tid = threadIdx.x;
    if (tid == 0) { s_carry = 0; rowptr[0] = 0; }
    __syncthreads();
    for (int base = 0; base < NN; base += 1024) {
        int i = base + tid;
        int v = (i < NN) ? cnt[i] : 0;
        sdata[tid] = v;
        __syncthreads();
        for (int off = 1; off < 1024; off <<= 1) {
            int t = (tid >= off) ? sdata[tid - off] : 0;
            __syncthreads();
            sdata[tid] += t;
            __syncthreads();
        }
        int total = sdata[1023];
        if (i < NN) rowptr[i + 1] = s_carry + sdata[tid];
        __syncthreads();
        if (tid == 0) s_carry += total;
        __syncthreads();
    }
}

__global__ __launch_bounds__(256) void scatter_k(const int* __restrict__ rec,
    const int* __restrict__ rowptr, int* __restrict__ cursor,
    int* __restrict__ colidx, int* __restrict__ seg)
{
    int e = blockIdx.x*256 + threadIdx.x;
    if (e < NE) {
        int r = rec[e];
        int pos = atomicAdd(&cursor[r], 1);
        colidx[rowptr[r] + pos] = e;
        seg[rowptr[r] + pos] = r;
    }
}

// ======================= fused gather + GEMM (+ fused segment-sum) =======
// B-fragments are read directly from global wf (516 KB, L2-resident) —
// no LDS staging, no staging barrier. LDS only used for the AGG tile.
template <int MODE, int KCH, bool AGG, bool A1F32>
__global__ __launch_bounds__(256, 4) void gemm_k(
    const bf16* __restrict__ A0, const bf16* __restrict__ A1, const float* __restrict__ A1f,
    const bf16* __restrict__ A2,
    const int* __restrict__ send, const int* __restrict__ rec, const int* __restrict__ gmap,
    const int* __restrict__ seg, const int* __restrict__ rowptr,
    const bf16* __restrict__ wf, const float* __restrict__ bias,
    bf16* __restrict__ out, float* __restrict__ out2, float* __restrict__ aggout,
    int n_rows)
{
    __shared__ __align__(16) char lds_raw[AGG ? AGG_BYTES : 16];
    int tid = threadIdx.x;
    int lane = tid & 63, wv = tid >> 6;
    int l15 = lane & 15, q = lane >> 4;
    long row_base = (long)blockIdx.x*256 + wv*64;

    int eclamp[4], sidx[4], ridx[4];
    #pragma unroll
    for (int et = 0; et < 4; ++et) {
        long r = row_base + et*16 + l15;
        int rc = (r < n_rows) ? (int)r : (n_rows - 1);
        eclamp[et] = rc;
        if constexpr (MODE == M_HMSG) {
            int em = gmap[rc];
            sidx[et] = send[em]; ridx[et] = rec[em];
        } else if constexpr (MODE == M_EMB16G) {
            sidx[et] = gmap[rc];
        }
    }

    auto load_frag = [&](int c, bf16x8s* dst) {
        #pragma unroll
        for (int et = 0; et < 4; ++et) {
            bf16x8s v = {0,0,0,0,0,0,0,0};
            if constexpr (MODE == M_EMB16) {
                if (q < 2) v = *(const bf16x8s*)(A0 + (long)eclamp[et]*16 + q*8);
            } else if constexpr (MODE == M_EMB16G) {
                if (q < 2) v = *(const bf16x8s*)(A0 + (long)sidx[et]*16 + q*8);
            } else if constexpr (MODE == M_EMB128) {
                v = *(const bf16x8s*)(A0 + (long)eclamp[et]*128 + c*32 + q*8);
            } else if constexpr (MODE == M_NODE2) {
                int sgi = c >> 1; int off = ((c & 1) << 5) + (q << 3);
                if (sgi == 0) {
                    v = *(const bf16x8s*)(A0 + (long)eclamp[et]*64 + off);
                } else if constexpr (A1F32) {
                    const float* fp = A1f + (long)eclamp[et]*64 + off;
                    float4 f0 = ((const float4*)fp)[0];
                    float4 f1 = ((const float4*)fp)[1];
                    bf16 tmp[8];
                    tmp[0]=__float2bfloat16(f0.x); tmp[1]=__float2bfloat16(f0.y);
                    tmp[2]=__float2bfloat16(f0.z); tmp[3]=__float2bfloat16(f0.w);
                    tmp[4]=__float2bfloat16(f1.x); tmp[5]=__float2bfloat16(f1.y);
                    tmp[6]=__float2bfloat16(f1.z); tmp[7]=__float2bfloat16(f1.w);
                    v = *(const bf16x8s*)tmp;
                } else {
                    v = *(const bf16x8s*)(A1 + (long)eclamp[et]*64 + off);
                }
            } else { // M_HMSG: [h[s],p[s],h[r],p[r],e]
                int sgi = c >> 1; int off = ((c & 1) << 5) + (q << 3);
                if (sgi == 4) {
                    v = __builtin_nontemporal_load((const bf16x8s*)(A2 + (long)eclamp[et]*64 + off));
                } else {
                    const bf16* b = (sgi == 0) ? A0 + (long)sidx[et]*64
                                  : (sgi == 1) ? A1 + (long)sidx[et]*64
                                  : (sgi == 2) ? A0 + (long)ridx[et]*64
                                               : A1 + (long)ridx[et]*64;
                    v = *(const bf16x8s*)(b + off);
                }
            }
            dst[et] = v;
        }
    };

    float bv[4];
    #pragma unroll
    for (int t = 0; t < 4; ++t) bv[t] = bias[t*16 + l15];

    f32x4 acc[4][4];
    #pragma unroll
    for (int et = 0; et < 4; ++et)
        #pragma unroll
        for (int t = 0; t < 4; ++t) {
            acc[et][t][0] = bv[t]; acc[et][t][1] = bv[t];
            acc[et][t][2] = bv[t]; acc[et][t][3] = bv[t];
        }

    bf16x8s af[2][4];
    load_frag(0, af[0]);
    #pragma unroll
    for (int c = 0; c < KCH; ++c) {
        if (c + 1 < KCH) load_frag(c + 1, af[(c + 1) & 1]);
        #pragma unroll
        for (int t = 0; t < 4; ++t) {
            bf16x8s bfv = *(const bf16x8s*)(wf + ((long)(c*4 + t)*64 + lane)*8);
            #pragma unroll
            for (int et = 0; et < 4; ++et)
                acc[et][t] = __builtin_amdgcn_mfma_f32_16x16x32_bf16(af[c & 1][et], bfv, acc[et][t], 0, 0, 0);
        }
    }

    if constexpr (AGG) {
        // ---- fused segment-sum epilogue (edges rec-sorted; NE % 256 == 0) ----
        bf16* sD = (bf16*)lds_raw;
        #pragma unroll
        for (int et = 0; et < 4; ++et)
            #pragma unroll
            for (int r = 0; r < 4; ++r)
                #pragma unroll
                for (int t = 0; t < 4; ++t)
                    sD[(wv*64 + et*16 + q*4 + r)*AGG_STRIDE + t*16 + l15] =
                        __float2bfloat16(acc[et][t][r]);
        __syncthreads();
        int col = tid & 63, wpart = tid >> 6;
        int gbase = blockIdx.x*256;
        int n0 = seg[gbase], n1 = seg[gbase + 255];
        for (int n = n0 + wpart; n <= n1; n += 4) {
            int beg = rowptr[n], end = rowptr[n + 1];
            if (beg < gbase) beg = gbase;
            if (end > gbase + 256) end = gbase + 256;
            if (beg < end) {
                float s = 0.0f;
                for (int j = beg; j < end; ++j)
                    s += __bfloat162float(sD[(j - gbase)*AGG_STRIDE + col]);
                atomicAdd(&aggout[(long)n*64 + col], s);
            }
        }
    } else {
        // D layout: row = q*4 + reg, col = t*16 + l15
        #pragma unroll
        for (int et = 0; et < 4; ++et) {
            #pragma unroll
            for (int r = 0; r < 4; ++r) {
                long row = row_base + et*16 + q*4 + r;
                if (row < n_rows) {
                    #pragma unroll
                    for (int t = 0; t < 4; ++t) {
                        float fv = acc[et][t][r];
                        out[row*64 + t*16 + l15] = __float2bfloat16(fv);
                        if (out2) out2[row*64 + t*16 + l15] = fv;
                    }
                }
            }
        }
    }
}

// ======================= fused EU + PM kernel =======================
// phase 1: e_new = [h[s],h[r],e] @ eu_W + b   (written NT to e_buf + staged in LDS)
// phase 2: p_msg = [p[s],p[r],e_new] @ pm_W + b  (e_new A-frags read from LDS)
// epilogue: segment-sum p_msg -> atomicAdd aggout (LDS tile reused)
__global__ __launch_bounds__(256, 4) void eupm_k(
    const bf16* __restrict__ hh, const bf16* __restrict__ pp, bf16* __restrict__ e_buf,
    const int* __restrict__ send, const int* __restrict__ rec, const int* __restrict__ gmap,
    const int* __restrict__ seg, const int* __restrict__ rowptr,
    const bf16* __restrict__ wf_eu, const bf16* __restrict__ wf_pm,
    const float* __restrict__ bias_eu, const float* __restrict__ bias_pm,
    float* __restrict__ aggout)
{
    __shared__ __align__(16) bf16 sE[256 * AGG_STRIDE];   // 36864 B
    int tid = threadIdx.x;
    int lane = tid & 63, wv = tid >> 6;
    int l15 = lane & 15, q = lane >> 4;
    int row0 = blockIdx.x*256;

    int erow[4], sidx[4], ridx[4];
    #pragma unroll
    for (int et = 0; et < 4; ++et) {
        int rc = row0 + wv*64 + et*16 + l15;   // NE % 256 == 0, no clamp
        erow[et] = rc;
        int em = gmap[rc];
        sidx[et] = send[em]; ridx[et] = rec[em];
    }

    f32x4 acc[4][4];

    // ---------------- phase 1: EU ----------------
    {
        float bv[4];
        #pragma unroll
        for (int t = 0; t < 4; ++t) bv[t] = bias_eu[t*16 + l15];
        #pragma unroll
        for (int et = 0; et < 4; ++et)
            #pragma unroll
            for (int t = 0; t < 4; ++t) {
                acc[et][t][0] = bv[t]; acc[et][t][1] = bv[t];
                acc[et][t][2] = bv[t]; acc[et][t][3] = bv[t];
            }
        auto load1 = [&](int c, bf16x8s* dst) {
            #pragma unroll
            for (int et = 0; et < 4; ++et) {
                int sgi = c >> 1, off = ((c & 1) << 5) + (q << 3);
                if (sgi == 2)
                    dst[et] = __builtin_nontemporal_load(
                        (const bf16x8s*)(e_buf + (long)erow[et]*64 + off));
                else {
                    const bf16* b = (sgi == 0) ? hh + (long)sidx[et]*64
                                               : hh + (long)ridx[et]*64;
                    dst[et] = *(const bf16x8s*)(b + off);
                }
            }
        };
        bf16x8s af[2][4];
        load1(0, af[0]);
        #pragma unroll
        for (int c = 0; c < 6; ++c) {
            if (c + 1 < 6) load1(c + 1, af[(c + 1) & 1]);
            #pragma unroll
            for (int t = 0; t < 4; ++t) {
                bf16x8s bfv = *(const bf16x8s*)(wf_eu + ((long)(c*4 + t)*64 + lane)*8);
                #pragma unroll
                for (int et = 0; et < 4; ++et)
                    acc[et][t] = __builtin_amdgcn_mfma_f32_16x16x32_bf16(af[c & 1][et], bfv, acc[et][t], 0, 0, 0);
            }
        }
    }
    // store e_new: LDS staging + NT global
    #pragma unroll
    for (int et = 0; et < 4; ++et)
        #pragma unroll
        for (int r = 0; r < 4; ++r) {
            int lr = wv*64 + et*16 + q*4 + r;
            #pragma unroll
            for (int t = 0; t < 4; ++t) {
                bf16 bvv = __float2bfloat16(acc[et][t][r]);
                sE[lr*AGG_STRIDE + t*16 + l15] = bvv;
                __builtin_nontemporal_store(*(const short*)&bvv,
                    (short*)&e_buf[(long)(row0 + lr)*64 + t*16 + l15]);
            }
        }
    __syncthreads();

    // ---------------- phase 2: PM ----------------
    {
        float bv[4];
        #pragma unroll
        for (int t = 0; t < 4; ++t) bv[t] = bias_pm[t*16 + l15];
        #pragma unroll
        for (int et = 0; et < 4; ++et)
            #pragma unroll
            for (int t = 0; t < 4; ++t) {
                acc[et][t][0] = bv[t]; acc[et][t][1] = bv[t];
                acc[et][t][2] = bv[t]; acc[et][t][3] = bv[t];
            }
        auto load2 = [&](int c, bf16x8s* dst) {
            #pragma unroll
            for (int et = 0; et < 4; ++et) {
                int sgi = c >> 1, off = ((c & 1) << 5) + (q << 3);
                if (sgi == 2)
                    dst[et] = *(const bf16x8s*)(sE + (wv*64 + et*16 + l15)*AGG_STRIDE + off);
                else {
                    const bf16* b = (sgi == 0) ? pp + (long)sidx[et]*64
                                               : pp + (long)ridx[et]*64;
                    dst[et] = *(const bf16x8s*)(b + off);
                }
            }
        };
        bf16x8s af[2][4];
        load2(0, af[0]);
        #pragma unroll
        for (int c = 0; c < 6; ++c) {
            if (c + 1 < 6) load2(c + 1, af[(c + 1) & 1]);
            #pragma unroll
            for (int t = 0; t < 4; ++t) {
                bf16x8s bfv = *(const bf16x8s*)(wf_pm + ((long)(c*4 + t)*64 + lane)*8);
                #pragma unroll
                for (int et = 0; et < 4; ++et)
                    acc[et][t] = __builtin_amdgcn_mfma_f32_16x16x32_bf16(af[c & 1][et], bfv, acc[et][t], 0, 0, 0);
            }
        }
    }
    __syncthreads();   // all sE A-reads done before overwrite

    // epilogue: stage p_msg, segment-sum, atomicAdd
    #pragma unroll
    for (int et = 0; et < 4; ++et)
        #pragma unroll
        for (int r = 0; r < 4; ++r)
            #pragma unroll
            for (int t = 0; t < 4; ++t)
                sE[(wv*64 + et*16 + q*4 + r)*AGG_STRIDE + t*16 + l15] =
                    __float2bfloat16(acc[et][t][r]);
    __syncthreads();
    int col = tid & 63, wpart = tid >> 6;
    int n0 = seg[row0], n1 = seg[row0 + 255];
    for (int n = n0 + wpart; n <= n1; n += 4) {
        int beg = rowptr[n], end = rowptr[n + 1];
        if (beg < row0) beg = row0;
        if (end > row0 + 256) end = row0 + 256;
        if (beg < end) {
            float s = 0.0f;
            for (int j = beg; j < end; ++j)
                s += __bfloat162float(sE[(j - row0)*AGG_STRIDE + col]);
            atomicAdd(&aggout[(long)n*64 + col], s);
        }
    }
}

// ======================= launch =======================
extern "C" void kernel_launch(void* const* d_in, const int* in_sizes, int n_in,
                              void* d_out, int out_size, void* d_ws, size_t ws_size,
                              hipStream_t stream)
{
    (void)in_sizes; (void)n_in; (void)out_size; (void)ws_size;
    const float* h_in = (const float*)d_in[0];
    const float* e_in = (const float*)d_in[1];
    const float* p_in = (const float*)d_in[2];
    const int*  ei   = (const int*)d_in[3];
    const int* send = ei;
    const int* rec  = ei + NE;
    const float* he_W = (const float*)d_in[4];  const float* he_b = (const float*)d_in[5];
    const float* ee_W = (const float*)d_in[6];  const float* ee_b = (const float*)d_in[7];
    const float* pe_W = (const float*)d_in[8];  const float* pe_b = (const float*)d_in[9];
    const float* hm_W = (const float*)d_in[10]; const float* hm_b = (const float*)d_in[11];
    const float* hu_W = (const float*)d_in[12]; const float* hu_b = (const float*)d_in[13];
    const float* eu_W = (const float*)d_in[14]; const float* eu_b = (const float*)d_in[15];
    const float* pm_W = (const float*)d_in[16]; const float* pm_b = (const float*)d_in[17];
    const float* pu_W = (const float*)d_in[18]; const float* pu_b = (const float*)d_in[19];

    char* ws = (char*)d_ws;
    bf16* e_buf = (bf16*)(ws + OFF_E);
    bf16* cvt_h = (bf16*)(ws + OFF_CVT_H);
    bf16* cvt_e = (bf16*)(ws + OFF_CVT_E);
    bf16* cvt_p = (bf16*)(ws + OFF_CVT_P);
    int*  segarr= (int*)(ws + OFF_SEG);
    float* haggf= (float*)(ws + OFF_HAGGF);
    float* paggf= (float*)(ws + OFF_PAGGF);
    bf16* h     = (bf16*)(ws + OFF_H);
    bf16* p     = (bf16*)(ws + OFF_P);
    bf16* wf    = (bf16*)(ws + OFF_WFMT);
    int* rowptr = (int*)(ws + OFF_ROWPTR);
    int* colidx = (int*)(ws + OFF_COLIDX);
    int* cnt    = (int*)(ws + OFF_CNT);
    float* dout = (float*)d_out;

    const int EB = NE / 256;          // 3125 blocks, exact
    const int NB = (NN + 255) / 256;  // 196 blocks

    // CSR build (by rec): colidx[j] = original edge id, seg[j] = rec node
    (void)hipMemsetAsync(cnt, 0, NN * sizeof(int), stream);
    hist_k<<<EB, 256, 0, stream>>>(rec, cnt);
    scan_k<<<1, 1024, 0, stream>>>(cnt, rowptr);
    (void)hipMemsetAsync(cnt, 0, NN * sizeof(int), stream);
    scatter_k<<<EB, 256, 0, stream>>>(rec, rowptr, cnt, colidx, segarr);

    // input conversion fp32 -> bf16
    cvt_k<<<(NN*128/4 + 255)/256, 256, 0, stream>>>(h_in, cvt_h, NN*128/4);
    cvt_k<<<(NE*16/4 + 255)/256, 256, 0, stream>>>(e_in, cvt_e, NE*16/4);
    cvt_k<<<(NN*16/4 + 255)/256, 256, 0, stream>>>(p_in, cvt_p, NN*16/4);

    // weight formatting
    wfmt_k<<<23, 256, 0, stream>>>(he_W, ee_W, pe_W, hm_W, hu_W, eu_W, pm_W, pu_W, wf);

    // embeddings (e lands directly in SORTED edge order via colidx gather)
    gemm_k<M_EMB128, 4, false, false><<<NB, 256, 0, stream>>>(cvt_h, nullptr, nullptr, nullptr,
        nullptr, nullptr, nullptr, nullptr, nullptr, wf + WOFF_HE, he_b, h, nullptr, nullptr, NN);
    gemm_k<M_EMB16G, 1, false, false><<<EB, 256, 0, stream>>>(cvt_e, nullptr, nullptr, nullptr,
        nullptr, nullptr, colidx, nullptr, nullptr, wf + WOFF_EE, ee_b, e_buf, nullptr, nullptr, NE);
    gemm_k<M_EMB16, 1, false, false><<<NB, 256, 0, stream>>>(cvt_p, nullptr, nullptr, nullptr,
        nullptr, nullptr, nullptr, nullptr, nullptr, wf + WOFF_PE, pe_b, p, nullptr, nullptr, NN);

    for (int i = 0; i < 4; ++i) {
        // h_agg = segment_sum([h[s],p[s],h[r],p[r],e] @ hm_W[i])  — fused
        (void)hipMemsetAsync(haggf, 0, (long)NN*64*sizeof(float), stream);
        gemm_k<M_HMSG, 10, true, false><<<EB, 256, 0, stream>>>(h, p, nullptr, e_buf,
            send, rec, colidx, segarr, rowptr,
            wf + WOFF_HM + (long)i*20480, hm_b + i*64, nullptr, nullptr, haggf, NE);
        // h = [h, h_agg] @ hu_W[i]   (A1 = fp32 aggregate)
        gemm_k<M_NODE2, 4, false, true><<<NB, 256, 0, stream>>>(h, nullptr, haggf, nullptr,
            nullptr, nullptr, nullptr, nullptr, nullptr,
            wf + WOFF_HU + (long)i*8192, hu_b + i*64, h, (i == 3) ? dout : nullptr, nullptr, NN);
        // fused: e_new = [h[s],h[r],e] @ eu_W; p_agg = segsum([p[s],p[r],e_new] @ pm_W)
        (void)hipMemsetAsync(paggf, 0, (long)NN*64*sizeof(float), stream);
        eupm_k<<<EB, 256, 0, stream>>>(h, p, e_buf, send, rec, colidx, segarr, rowptr,
            wf + WOFF_EU + (long)i*12288, wf + WOFF_PM + (long)i*12288,
            eu_b + i*64, pm_b + i*64, paggf);
        // p = [p, p_agg] @ pu_W[i]
        gemm_k<M_NODE2, 4, false, true><<<NB, 256, 0, stream>>>(p, nullptr, paggf, nullptr,
            nullptr, nullptr, nullptr, nullptr, nullptr,
            wf + WOFF_PU + (long)i*8192, pu_b + i*64, p, (i == 3) ? dout + (long)NN*64 : nullptr, nullptr, NN);
    }
}

// Round 8
// 1470.692 us; speedup vs baseline: 1.3273x; 1.0023x over previous
//
#include <hip/hip_runtime.h>
#include <hip/hip_bf16.h>

#define NN 50000
#define NE 800000

typedef __hip_bfloat16 bf16;
typedef __attribute__((ext_vector_type(8))) short bf16x8s;   // 8 bf16 = 4 VGPRs
typedef __attribute__((ext_vector_type(4))) float f32x4;

// ---- workspace layout (bytes) ----
#define OFF_E      0L            // e buffer (SORTED edge order) [NE,64] bf16
#define OFF_CVT_H  102400000L    //   h_in bf16 [NN,128]
#define OFF_CVT_E  115200000L    //   e_in bf16 [NE,16]
#define OFF_CVT_P  140800000L    //   p_in bf16 [NN,16]
#define OFF_SEG    147400000L    //   seg[j] = rec of sorted edge j, NE int
#define OFF_HAGGF  160000000L    //   h_agg fp32 [NN,64] = 12.8 MB
#define OFF_PAGGF  172800000L    //   p_agg fp32 [NN,64] = 12.8 MB
#define OFF_H      204800000L    // h  [NN,64] bf16
#define OFF_P      211200000L    // p
#define OFF_WFMT   230400000L    // formatted weights, 258048 bf16 (L2-resident)
#define OFF_ROWPTR 230916096L    // (NN+1) int
#define OFF_COLIDX 231116104L    // NE int  (sorted-pos j -> original edge id)
#define OFF_CNT    234316104L    // NN int

// ---- formatted-weight element offsets ----
#define WOFF_HE 0
#define WOFF_EE 8192
#define WOFF_PE 10240
#define WOFF_HM 12288       // 4 x 20480
#define WOFF_HU 94208       // 4 x 8192
#define WOFF_EU 126976      // 4 x 12288
#define WOFF_PM 176128      // 4 x 12288
#define WOFF_PU 225280      // 4 x 8192

// gather modes
#define M_EMB16  0
#define M_EMB128 1
#define M_NODE2  2
#define M_HMSG   4
#define M_EMB16G 5

// agg / e_new staging tile: 256 rows x stride 72 bf16 (pad kills conflicts)
#define AGG_STRIDE 72
#define AGG_BYTES  (256 * AGG_STRIDE * 2)   // 36864

// ======================= fp32 -> bf16 conversion =======================
__global__ __launch_bounds__(256) void cvt_k(const float* __restrict__ src,
                                             bf16* __restrict__ dst, int n4)
{
    int i = blockIdx.x*256 + threadIdx.x;
    if (i < n4) {
        float4 v = ((const float4*)src)[i];
        dst[i*4+0] = __float2bfloat16(v.x);
        dst[i*4+1] = __float2bfloat16(v.y);
        dst[i*4+2] = __float2bfloat16(v.z);
        dst[i*4+3] = __float2bfloat16(v.w);
    }
}

// ======================= weight formatting (fp32 -> bf16 B-fragments) ==
__global__ __launch_bounds__(256) void wfmt_k(
    const float* __restrict__ he, const float* __restrict__ ee, const float* __restrict__ pe,
    const float* __restrict__ hm, const float* __restrict__ hu, const float* __restrict__ eu,
    const float* __restrict__ pm, const float* __restrict__ pu, bf16* __restrict__ wf)
{
    int s = blockIdx.x;
    const float* src; int Ksrc, Kpad; long doff;
    if      (s == 0) { src = he; Ksrc = 128; Kpad = 128; doff = WOFF_HE; }
    else if (s == 1) { src = ee; Ksrc = 16;  Kpad = 32;  doff = WOFF_EE; }
    else if (s == 2) { src = pe; Ksrc = 16;  Kpad = 32;  doff = WOFF_PE; }
    else if (s < 7)  { int i = s - 3;  src = hm + (long)i*320*64; Ksrc = 320; Kpad = 320; doff = WOFF_HM + (long)i*20480; }
    else if (s < 11) { int i = s - 7;  src = hu + (long)i*128*64; Ksrc = 128; Kpad = 128; doff = WOFF_HU + (long)i*8192; }
    else if (s < 15) { int i = s - 11; src = eu + (long)i*192*64; Ksrc = 192; Kpad = 192; doff = WOFF_EU + (long)i*12288; }
    else if (s < 19) { int i = s - 15; src = pm + (long)i*192*64; Ksrc = 192; Kpad = 192; doff = WOFF_PM + (long)i*12288; }
    else             { int i = s - 19; src = pu + (long)i*128*64; Ksrc = 128; Kpad = 128; doff = WOFF_PU + (long)i*8192; }
    int total = Kpad * 64;
    for (int idx = threadIdx.x; idx < total; idx += blockDim.x) {
        int j = idx & 7, l = (idx >> 3) & 63, ct = idx >> 9;
        int c = ct >> 2, t = ct & 3;
        int k = c*32 + (l >> 4)*8 + j;
        int n = t*16 + (l & 15);
        wf[doff + idx] = (k < Ksrc) ? __float2bfloat16(src[(long)k*64 + n])
                                    : __float2bfloat16(0.0f);
    }
}

// ======================= CSR build =======================
__global__ __launch_bounds__(256) void hist_k(const int* __restrict__ rec, int* __restrict__ cnt)
{
    int e = blockIdx.x*256 + threadIdx.x;
    if (e < NE) atomicAdd(&cnt[rec[e]], 1);
}

__global__ __launch_bounds__(1024) void scan_k(const int* __restrict__ cnt, int* __restrict__ rowptr)
{
    __shared__ int sdata[1024];
    __shared__ int s_carry;
    int tid = threadIdx.x;
    if (tid == 0) { s_carry = 0; rowptr[0] = 0; }
    __syncthreads();
    for (int base = 0; base < NN; base += 1024) {
        int i = base + tid;
        int v = (i < NN) ? cnt[i] : 0;
        sdata[tid] = v;
        __syncthreads();
        for (int off = 1; off < 1024; off <<= 1) {
            int t = (tid >= off) ? sdata[tid - off] : 0;
            __syncthreads();
            sdata[tid] += t;
            __syncthreads();
        }
        int total = sdata[1023];
        if (i < NN) rowptr[i + 1] = s_carry + sdata[tid];
        __syncthreads();
        if (tid == 0) s_carry += total;
        __syncthreads();
    }
}

__global__ __launch_bounds__(256) void scatter_k(const int* __restrict__ rec,
    const int* __restrict__ rowptr, int* __restrict__ cursor,
    int* __restrict__ colidx, int* __restrict__ seg)
{
    int e = blockIdx.x*256 + threadIdx.x;
    if (e < NE) {
        int r = rec[e];
        int pos = atomicAdd(&cursor[r], 1);
        colidx[rowptr[r] + pos] = e;
        seg[rowptr[r] + pos] = r;
    }
}

// ======================= fused gather + GEMM (+ fused segment-sum) =======
// B-fragments are read directly from global wf (516 KB, L2-resident) —
// no LDS staging, no staging barrier. LDS only used for the AGG tile.
// NO nontemporal hints anywhere: the per-layer working set (~141 MB) fits
// the 256 MB Infinity Cache; nt bypasses it and forces HBM round-trips.
template <int MODE, int KCH, bool AGG, bool A1F32>
__global__ __launch_bounds__(256, 4) void gemm_k(
    const bf16* __restrict__ A0, const bf16* __restrict__ A1, const float* __restrict__ A1f,
    const bf16* __restrict__ A2,
    const int* __restrict__ send, const int* __restrict__ rec, const int* __restrict__ gmap,
    const int* __restrict__ seg, const int* __restrict__ rowptr,
    const bf16* __restrict__ wf, const float* __restrict__ bias,
    bf16* __restrict__ out, float* __restrict__ out2, float* __restrict__ aggout,
    int n_rows)
{
    __shared__ __align__(16) char lds_raw[AGG ? AGG_BYTES : 16];
    int tid = threadIdx.x;
    int lane = tid & 63, wv = tid >> 6;
    int l15 = lane & 15, q = lane >> 4;
    long row_base = (long)blockIdx.x*256 + wv*64;

    int eclamp[4], sidx[4], ridx[4];
    #pragma unroll
    for (int et = 0; et < 4; ++et) {
        long r = row_base + et*16 + l15;
        int rc = (r < n_rows) ? (int)r : (n_rows - 1);
        eclamp[et] = rc;
        if constexpr (MODE == M_HMSG) {
            int em = gmap[rc];
            sidx[et] = send[em]; ridx[et] = rec[em];
        } else if constexpr (MODE == M_EMB16G) {
            sidx[et] = gmap[rc];
        }
    }

    auto load_frag = [&](int c, bf16x8s* dst) {
        #pragma unroll
        for (int et = 0; et < 4; ++et) {
            bf16x8s v = {0,0,0,0,0,0,0,0};
            if constexpr (MODE == M_EMB16) {
                if (q < 2) v = *(const bf16x8s*)(A0 + (long)eclamp[et]*16 + q*8);
            } else if constexpr (MODE == M_EMB16G) {
                if (q < 2) v = *(const bf16x8s*)(A0 + (long)sidx[et]*16 + q*8);
            } else if constexpr (MODE == M_EMB128) {
                v = *(const bf16x8s*)(A0 + (long)eclamp[et]*128 + c*32 + q*8);
            } else if constexpr (MODE == M_NODE2) {
                int sgi = c >> 1; int off = ((c & 1) << 5) + (q << 3);
                if (sgi == 0) {
                    v = *(const bf16x8s*)(A0 + (long)eclamp[et]*64 + off);
                } else if constexpr (A1F32) {
                    const float* fp = A1f + (long)eclamp[et]*64 + off;
                    float4 f0 = ((const float4*)fp)[0];
                    float4 f1 = ((const float4*)fp)[1];
                    bf16 tmp[8];
                    tmp[0]=__float2bfloat16(f0.x); tmp[1]=__float2bfloat16(f0.y);
                    tmp[2]=__float2bfloat16(f0.z); tmp[3]=__float2bfloat16(f0.w);
                    tmp[4]=__float2bfloat16(f1.x); tmp[5]=__float2bfloat16(f1.y);
                    tmp[6]=__float2bfloat16(f1.z); tmp[7]=__float2bfloat16(f1.w);
                    v = *(const bf16x8s*)tmp;
                } else {
                    v = *(const bf16x8s*)(A1 + (long)eclamp[et]*64 + off);
                }
            } else { // M_HMSG: [h[s],p[s],h[r],p[r],e]
                int sgi = c >> 1; int off = ((c & 1) << 5) + (q << 3);
                if (sgi == 4) {
                    v = *(const bf16x8s*)(A2 + (long)eclamp[et]*64 + off);
                } else {
                    const bf16* b = (sgi == 0) ? A0 + (long)sidx[et]*64
                                  : (sgi == 1) ? A1 + (long)sidx[et]*64
                                  : (sgi == 2) ? A0 + (long)ridx[et]*64
                                               : A1 + (long)ridx[et]*64;
                    v = *(const bf16x8s*)(b + off);
                }
            }
            dst[et] = v;
        }
    };

    float bv[4];
    #pragma unroll
    for (int t = 0; t < 4; ++t) bv[t] = bias[t*16 + l15];

    f32x4 acc[4][4];
    #pragma unroll
    for (int et = 0; et < 4; ++et)
        #pragma unroll
        for (int t = 0; t < 4; ++t) {
            acc[et][t][0] = bv[t]; acc[et][t][1] = bv[t];
            acc[et][t][2] = bv[t]; acc[et][t][3] = bv[t];
        }

    bf16x8s af[2][4];
    load_frag(0, af[0]);
    #pragma unroll
    for (int c = 0; c < KCH; ++c) {
        if (c + 1 < KCH) load_frag(c + 1, af[(c + 1) & 1]);
        #pragma unroll
        for (int t = 0; t < 4; ++t) {
            bf16x8s bfv = *(const bf16x8s*)(wf + ((long)(c*4 + t)*64 + lane)*8);
            #pragma unroll
            for (int et = 0; et < 4; ++et)
                acc[et][t] = __builtin_amdgcn_mfma_f32_16x16x32_bf16(af[c & 1][et], bfv, acc[et][t], 0, 0, 0);
        }
    }

    if constexpr (AGG) {
        // ---- fused segment-sum epilogue (edges rec-sorted; NE % 256 == 0) ----
        bf16* sD = (bf16*)lds_raw;
        #pragma unroll
        for (int et = 0; et < 4; ++et)
            #pragma unroll
            for (int r = 0; r < 4; ++r)
                #pragma unroll
                for (int t = 0; t < 4; ++t)
                    sD[(wv*64 + et*16 + q*4 + r)*AGG_STRIDE + t*16 + l15] =
                        __float2bfloat16(acc[et][t][r]);
        __syncthreads();
        int col = tid & 63, wpart = tid >> 6;
        int gbase = blockIdx.x*256;
        int n0 = seg[gbase], n1 = seg[gbase + 255];
        for (int n = n0 + wpart; n <= n1; n += 4) {
            int beg = rowptr[n], end = rowptr[n + 1];
            if (beg < gbase) beg = gbase;
            if (end > gbase + 256) end = gbase + 256;
            if (beg < end) {
                float s = 0.0f;
                for (int j = beg; j < end; ++j)
                    s += __bfloat162float(sD[(j - gbase)*AGG_STRIDE + col]);
                atomicAdd(&aggout[(long)n*64 + col], s);
            }
        }
    } else {
        // D layout: row = q*4 + reg, col = t*16 + l15
        #pragma unroll
        for (int et = 0; et < 4; ++et) {
            #pragma unroll
            for (int r = 0; r < 4; ++r) {
                long row = row_base + et*16 + q*4 + r;
                if (row < n_rows) {
                    #pragma unroll
                    for (int t = 0; t < 4; ++t) {
                        float fv = acc[et][t][r];
                        out[row*64 + t*16 + l15] = __float2bfloat16(fv);
                        if (out2) out2[row*64 + t*16 + l15] = fv;
                    }
                }
            }
        }
    }
}

// ======================= fused EU + PM kernel =======================
// phase 1: e_new = [h[s],h[r],e] @ eu_W + b   (written to e_buf + staged in LDS)
// phase 2: p_msg = [p[s],p[r],e_new] @ pm_W + b  (e_new A-frags read from LDS)
// epilogue: segment-sum p_msg -> atomicAdd aggout (LDS tile reused)
__global__ __launch_bounds__(256, 4) void eupm_k(
    const bf16* __restrict__ hh, const bf16* __restrict__ pp, bf16* __restrict__ e_buf,
    const int* __restrict__ send, const int* __restrict__ rec, const int* __restrict__ gmap,
    const int* __restrict__ seg, const int* __restrict__ rowptr,
    const bf16* __restrict__ wf_eu, const bf16* __restrict__ wf_pm,
    const float* __restrict__ bias_eu, const float* __restrict__ bias_pm,
    float* __restrict__ aggout)
{
    __shared__ __align__(16) bf16 sE[256 * AGG_STRIDE];   // 36864 B
    int tid = threadIdx.x;
    int lane = tid & 63, wv = tid >> 6;
    int l15 = lane & 15, q = lane >> 4;
    int row0 = blockIdx.x*256;

    int erow[4], sidx[4], ridx[4];
    #pragma unroll
    for (int et = 0; et < 4; ++et) {
        int rc = row0 + wv*64 + et*16 + l15;   // NE % 256 == 0, no clamp
        erow[et] = rc;
        int em = gmap[rc];
        sidx[et] = send[em]; ridx[et] = rec[em];
    }

    f32x4 acc[4][4];

    // ---------------- phase 1: EU ----------------
    {
        float bv[4];
        #pragma unroll
        for (int t = 0; t < 4; ++t) bv[t] = bias_eu[t*16 + l15];
        #pragma unroll
        for (int et = 0; et < 4; ++et)
            #pragma unroll
            for (int t = 0; t < 4; ++t) {
                acc[et][t][0] = bv[t]; acc[et][t][1] = bv[t];
                acc[et][t][2] = bv[t]; acc[et][t][3] = bv[t];
            }
        auto load1 = [&](int c, bf16x8s* dst) {
            #pragma unroll
            for (int et = 0; et < 4; ++et) {
                int sgi = c >> 1, off = ((c & 1) << 5) + (q << 3);
                if (sgi == 2)
                    dst[et] = *(const bf16x8s*)(e_buf + (long)erow[et]*64 + off);
                else {
                    const bf16* b = (sgi == 0) ? hh + (long)sidx[et]*64
                                               : hh + (long)ridx[et]*64;
                    dst[et] = *(const bf16x8s*)(b + off);
                }
            }
        };
        bf16x8s af[2][4];
        load1(0, af[0]);
        #pragma unroll
        for (int c = 0; c < 6; ++c) {
            if (c + 1 < 6) load1(c + 1, af[(c + 1) & 1]);
            #pragma unroll
            for (int t = 0; t < 4; ++t) {
                bf16x8s bfv = *(const bf16x8s*)(wf_eu + ((long)(c*4 + t)*64 + lane)*8);
                #pragma unroll
                for (int et = 0; et < 4; ++et)
                    acc[et][t] = __builtin_amdgcn_mfma_f32_16x16x32_bf16(af[c & 1][et], bfv, acc[et][t], 0, 0, 0);
            }
        }
    }
    // store e_new: LDS staging + global
    #pragma unroll
    for (int et = 0; et < 4; ++et)
        #pragma unroll
        for (int r = 0; r < 4; ++r) {
            int lr = wv*64 + et*16 + q*4 + r;
            #pragma unroll
            for (int t = 0; t < 4; ++t) {
                bf16 bvv = __float2bfloat16(acc[et][t][r]);
                sE[lr*AGG_STRIDE + t*16 + l15] = bvv;
                e_buf[(long)(row0 + lr)*64 + t*16 + l15] = bvv;
            }
        }
    __syncthreads();

    // ---------------- phase 2: PM ----------------
    {
        float bv[4];
        #pragma unroll
        for (int t = 0; t < 4; ++t) bv[t] = bias_pm[t*16 + l15];
        #pragma unroll
        for (int et = 0; et < 4; ++et)
            #pragma unroll
            for (int t = 0; t < 4; ++t) {
                acc[et][t][0] = bv[t]; acc[et][t][1] = bv[t];
                acc[et][t][2] = bv[t]; acc[et][t][3] = bv[t];
            }
        auto load2 = [&](int c, bf16x8s* dst) {
            #pragma unroll
            for (int et = 0; et < 4; ++et) {
                int sgi = c >> 1, off = ((c & 1) << 5) + (q << 3);
                if (sgi == 2)
                    dst[et] = *(const bf16x8s*)(sE + (wv*64 + et*16 + l15)*AGG_STRIDE + off);
                else {
                    const bf16* b = (sgi == 0) ? pp + (long)sidx[et]*64
                                               : pp + (long)ridx[et]*64;
                    dst[et] = *(const bf16x8s*)(b + off);
                }
            }
        };
        bf16x8s af[2][4];
        load2(0, af[0]);
        #pragma unroll
        for (int c = 0; c < 6; ++c) {
            if (c + 1 < 6) load2(c + 1, af[(c + 1) & 1]);
            #pragma unroll
            for (int t = 0; t < 4; ++t) {
                bf16x8s bfv = *(const bf16x8s*)(wf_pm + ((long)(c*4 + t)*64 + lane)*8);
                #pragma unroll
                for (int et = 0; et < 4; ++et)
                    acc[et][t] = __builtin_amdgcn_mfma_f32_16x16x32_bf16(af[c & 1][et], bfv, acc[et][t], 0, 0, 0);
            }
        }
    }
    __syncthreads();   // all sE A-reads done before overwrite

    // epilogue: stage p_msg, segment-sum, atomicAdd
    #pragma unroll
    for (int et = 0; et < 4; ++et)
        #pragma unroll
        for (int r = 0; r < 4; ++r)
            #pragma unroll
            for (int t = 0; t < 4; ++t)
                sE[(wv*64 + et*16 + q*4 + r)*AGG_STRIDE + t*16 + l15] =
                    __float2bfloat16(acc[et][t][r]);
    __syncthreads();
    int col = tid & 63, wpart = tid >> 6;
    int n0 = seg[row0], n1 = seg[row0 + 255];
    for (int n = n0 + wpart; n <= n1; n += 4) {
        int beg = rowptr[n], end = rowptr[n + 1];
        if (beg < row0) beg = row0;
        if (end > row0 + 256) end = row0 + 256;
        if (beg < end) {
            float s = 0.0f;
            for (int j = beg; j < end; ++j)
                s += __bfloat162float(sE[(j - row0)*AGG_STRIDE + col]);
            atomicAdd(&aggout[(long)n*64 + col], s);
        }
    }
}

// ======================= launch =======================
extern "C" void kernel_launch(void* const* d_in, const int* in_sizes, int n_in,
                              void* d_out, int out_size, void* d_ws, size_t ws_size,
                              hipStream_t stream)
{
    (void)in_sizes; (void)n_in; (void)out_size; (void)ws_size;
    const float* h_in = (const float*)d_in[0];
    const float* e_in = (const float*)d_in[1];
    const float* p_in = (const float*)d_in[2];
    const int*  ei   = (const int*)d_in[3];
    const int* send = ei;
    const int* rec  = ei + NE;
    const float* he_W = (const float*)d_in[4];  const float* he_b = (const float*)d_in[5];
    const float* ee_W = (const float*)d_in[6];  const float* ee_b = (const float*)d_in[7];
    const float* pe_W = (const float*)d_in[8];  const float* pe_b = (const float*)d_in[9];
    const float* hm_W = (const float*)d_in[10]; const float* hm_b = (const float*)d_in[11];
    const float* hu_W = (const float*)d_in[12]; const float* hu_b = (const float*)d_in[13];
    const float* eu_W = (const float*)d_in[14]; const float* eu_b = (const float*)d_in[15];
    const float* pm_W = (const float*)d_in[16]; const float* pm_b = (const float*)d_in[17];
    const float* pu_W = (const float*)d_in[18]; const float* pu_b = (const float*)d_in[19];

    char* ws = (char*)d_ws;
    bf16* e_buf = (bf16*)(ws + OFF_E);
    bf16* cvt_h = (bf16*)(ws + OFF_CVT_H);
    bf16* cvt_e = (bf16*)(ws + OFF_CVT_E);
    bf16* cvt_p = (bf16*)(ws + OFF_CVT_P);
    int*  segarr= (int*)(ws + OFF_SEG);
    float* haggf= (float*)(ws + OFF_HAGGF);
    float* paggf= (float*)(ws + OFF_PAGGF);
    bf16* h     = (bf16*)(ws + OFF_H);
    bf16* p     = (bf16*)(ws + OFF_P);
    bf16* wf    = (bf16*)(ws + OFF_WFMT);
    int* rowptr = (int*)(ws + OFF_ROWPTR);
    int* colidx = (int*)(ws + OFF_COLIDX);
    int* cnt    = (int*)(ws + OFF_CNT);
    float* dout = (float*)d_out;

    const int EB = NE / 256;          // 3125 blocks, exact
    const int NB = (NN + 255) / 256;  // 196 blocks

    // CSR build (by rec): colidx[j] = original edge id, seg[j] = rec node
    (void)hipMemsetAsync(cnt, 0, NN * sizeof(int), stream);
    hist_k<<<EB, 256, 0, stream>>>(rec, cnt);
    scan_k<<<1, 1024, 0, stream>>>(cnt, rowptr);
    (void)hipMemsetAsync(cnt, 0, NN * sizeof(int), stream);
    scatter_k<<<EB, 256, 0, stream>>>(rec, rowptr, cnt, colidx, segarr);

    // input conversion fp32 -> bf16
    cvt_k<<<(NN*128/4 + 255)/256, 256, 0, stream>>>(h_in, cvt_h, NN*128/4);
    cvt_k<<<(NE*16/4 + 255)/256, 256, 0, stream>>>(e_in, cvt_e, NE*16/4);
    cvt_k<<<(NN*16/4 + 255)/256, 256, 0, stream>>>(p_in, cvt_p, NN*16/4);

    // weight formatting
    wfmt_k<<<23, 256, 0, stream>>>(he_W, ee_W, pe_W, hm_W, hu_W, eu_W, pm_W, pu_W, wf);

    // embeddings (e lands directly in SORTED edge order via colidx gather)
    gemm_k<M_EMB128, 4, false, false><<<NB, 256, 0, stream>>>(cvt_h, nullptr, nullptr, nullptr,
        nullptr, nullptr, nullptr, nullptr, nullptr, wf + WOFF_HE, he_b, h, nullptr, nullptr, NN);
    gemm_k<M_EMB16G, 1, false, false><<<EB, 256, 0, stream>>>(cvt_e, nullptr, nullptr, nullptr,
        nullptr, nullptr, colidx, nullptr, nullptr, wf + WOFF_EE, ee_b, e_buf, nullptr, nullptr, NE);
    gemm_k<M_EMB16, 1, false, false><<<NB, 256, 0, stream>>>(cvt_p, nullptr, nullptr, nullptr,
        nullptr, nullptr, nullptr, nullptr, nullptr, wf + WOFF_PE, pe_b, p, nullptr, nullptr, NN);

    for (int i = 0; i < 4; ++i) {
        // h_agg = segment_sum([h[s],p[s],h[r],p[r],e] @ hm_W[i])  — fused
        (void)hipMemsetAsync(haggf, 0, (long)NN*64*sizeof(float), stream);
        gemm_k<M_HMSG, 10, true, false><<<EB, 256, 0, stream>>>(h, p, nullptr, e_buf,
            send, rec, colidx, segarr, rowptr,
            wf + WOFF_HM + (long)i*20480, hm_b + i*64, nullptr, nullptr, haggf, NE);
        // h = [h, h_agg] @ hu_W[i]   (A1 = fp32 aggregate)
        gemm_k<M_NODE2, 4, false, true><<<NB, 256, 0, stream>>>(h, nullptr, haggf, nullptr,
            nullptr, nullptr, nullptr, nullptr, nullptr,
            wf + WOFF_HU + (long)i*8192, hu_b + i*64, h, (i == 3) ? dout : nullptr, nullptr, NN);
        // fused: e_new = [h[s],h[r],e] @ eu_W; p_agg = segsum([p[s],p[r],e_new] @ pm_W)
        (void)hipMemsetAsync(paggf, 0, (long)NN*64*sizeof(float), stream);
        eupm_k<<<EB, 256, 0, stream>>>(h, p, e_buf, send, rec, colidx, segarr, rowptr,
            wf + WOFF_EU + (long)i*12288, wf + WOFF_PM + (long)i*12288,
            eu_b + i*64, pm_b + i*64, paggf);
        // p = [p, p_agg] @ pu_W[i]
        gemm_k<M_NODE2, 4, false, true><<<NB, 256, 0, stream>>>(p, nullptr, paggf, nullptr,
            nullptr, nullptr, nullptr, nullptr, nullptr,
            wf + WOFF_PU + (long)i*8192, pu_b + i*64, p, (i == 3) ? dout + (long)NN*64 : nullptr, nullptr, NN);
    }
}

// Round 10
// 1461.799 us; speedup vs baseline: 1.3354x; 1.0061x over previous
//
#include <hip/hip_runtime.h>
#include <hip/hip_bf16.h>

#define NN 50000
#define NE 800000

typedef __hip_bfloat16 bf16;
typedef __attribute__((ext_vector_type(8))) short bf16x8s;   // 8 bf16 = 4 VGPRs
typedef __attribute__((ext_vector_type(4))) float f32x4;

// ---- workspace layout (bytes) ----
#define OFF_E      0L            // e buffer (SORTED edge order) [NE,64] bf16 = 102.4 MB
#define OFF_AS     102400000L    // A_send [NN,64] bf16
#define OFF_ARF    108800000L    // A_rec  [NN,64] fp32  (fp32: deg-amplified, can't round)
#define OFF_BCS    121600000L    // BC_s   [NN,128] bf16 (B_s | C_s)
#define OFF_BR     134400000L    // B_r    [NN,64] bf16
#define OFF_CRF    140800000L    // C_r    [NN,64] fp32
#define OFF_H      153600000L    // h      [NN,64] bf16
#define OFF_P      160000000L    // p      [NN,64] bf16
#define OFF_HAGGF  166400000L    // h_agg accum fp32 [NN,64]
#define OFF_PAGGF  179200000L    // p_agg accum fp32 [NN,64]
#define OFF_WFMT   192000000L    // formatted weights 307200 bf16 = 614400 B
#define OFF_ROWPTR 192614400L    // (NN+1) int
#define OFF_COLIDX 192814404L    // NE int (sorted j -> original edge id)
#define OFF_SEG    196014404L    // NE int (rec of sorted edge j)
#define OFF_CNT    199214404L    // NN int (ends as deg)

// ---- formatted-weight element offsets (bf16 elems) ----
#define FW_HE 0
#define FW_EE 8192
#define FW_PE 10240
#define FW_L0 12288
#define LSTR  73728
#define R_HMS  0        // hm rows[0:128]   (A_send: [h|p])
#define R_HMR  8192     // hm rows[128:256] (A_rec)
#define R_W3HM 16384    // hm rows[256:320] (K=64)
#define R_HU   20480    // hu [128,64]
#define R_EUS  28672    // eu rows[0:64]
#define R_EUR  32768    // eu rows[64:128]
#define R_CEU  36864    // [[I],[I],[eu rows 128:192]] K=192
#define R_PMS  49152    // pm rows[0:64]
#define R_PMR  53248    // pm rows[64:128]
#define R_CPM  57344    // [[I],[pm rows 128:192]] K=128
#define R_PU   65536    // pu [128,64]

#define AGG_STRIDE 72

__device__ __forceinline__ bf16x8s bfrag(const bf16* w, int c, int t, int lane) {
    return *(const bf16x8s*)(w + ((long)(c*4 + t)*64 + lane)*8);
}
__device__ __forceinline__ bf16x8s cvt8(const float* fp) {
    float4 f0 = ((const float4*)fp)[0];
    float4 f1 = ((const float4*)fp)[1];
    bf16 tmp[8];
    tmp[0]=__float2bfloat16(f0.x); tmp[1]=__float2bfloat16(f0.y);
    tmp[2]=__float2bfloat16(f0.z); tmp[3]=__float2bfloat16(f0.w);
    tmp[4]=__float2bfloat16(f1.x); tmp[5]=__float2bfloat16(f1.y);
    tmp[6]=__float2bfloat16(f1.z); tmp[7]=__float2bfloat16(f1.w);
    return *(const bf16x8s*)tmp;
}

// ======================= weight formatting =======================
__global__ __launch_bounds__(256) void wfmt_k(
    const float* __restrict__ he, const float* __restrict__ ee, const float* __restrict__ pe,
    const float* __restrict__ hm, const float* __restrict__ hu, const float* __restrict__ eu,
    const float* __restrict__ pm, const float* __restrict__ pu, bf16* __restrict__ wf)
{
    int s = blockIdx.x;
    const float* src = nullptr; int rowoff = 0, Ksrc = 0, Kpad = 0, mode = 0; long doff = 0;
    if      (s == 0) { src = he; Ksrc = 128; Kpad = 128; doff = FW_HE; }
    else if (s == 1) { src = ee; Ksrc = 16;  Kpad = 32;  doff = FW_EE; }
    else if (s == 2) { src = pe; Ksrc = 16;  Kpad = 32;  doff = FW_PE; }
    else {
        int i = (s - 3) / 11, g = (s - 3) % 11;
        long base = FW_L0 + (long)i*LSTR;
        const float* HM = hm + (long)i*320*64;
        const float* HU = hu + (long)i*128*64;
        const float* EU = eu + (long)i*192*64;
        const float* PM = pm + (long)i*192*64;
        const float* PU = pu + (long)i*128*64;
        switch (g) {
          case 0:  src=HM; rowoff=0;   Ksrc=128; Kpad=128; doff=base+R_HMS;  break;
          case 1:  src=HM; rowoff=128; Ksrc=128; Kpad=128; doff=base+R_HMR;  break;
          case 2:  src=HM; rowoff=256; Ksrc=64;  Kpad=64;  doff=base+R_W3HM; break;
          case 3:  src=HU; rowoff=0;   Ksrc=128; Kpad=128; doff=base+R_HU;   break;
          case 4:  src=EU; rowoff=0;   Ksrc=64;  Kpad=64;  doff=base+R_EUS;  break;
          case 5:  src=EU; rowoff=64;  Ksrc=64;  Kpad=64;  doff=base+R_EUR;  break;
          case 6:  src=EU; rowoff=128; Kpad=192; mode=3;   doff=base+R_CEU;  break;
          case 7:  src=PM; rowoff=0;   Ksrc=64;  Kpad=64;  doff=base+R_PMS;  break;
          case 8:  src=PM; rowoff=64;  Ksrc=64;  Kpad=64;  doff=base+R_PMR;  break;
          case 9:  src=PM; rowoff=128; Kpad=128; mode=2;   doff=base+R_CPM;  break;
          default: src=PU; rowoff=0;   Ksrc=128; Kpad=128; doff=base+R_PU;   break;
        }
    }
    int total = Kpad * 64;
    for (int idx = threadIdx.x; idx < total; idx += 256) {
        int j = idx & 7, l = (idx >> 3) & 63, ct = idx >> 9;
        int c = ct >> 2, t = ct & 3;
        int k = c*32 + (l >> 4)*8 + j;
        int n = t*16 + (l & 15);
        float v;
        if (mode == 2)      v = (k < 64) ? ((k == n) ? 1.f : 0.f)
                                         : src[(long)(rowoff + k - 64)*64 + n];
        else if (mode == 3) v = (k < 64) ? ((k == n) ? 1.f : 0.f)
                              : (k < 128) ? ((k - 64 == n) ? 1.f : 0.f)
                                          : src[(long)(rowoff + k - 128)*64 + n];
        else                v = (k < Ksrc) ? src[(long)(rowoff + k)*64 + n] : 0.f;
        wf[doff + idx] = __float2bfloat16(v);
    }
}

// ======================= CSR build =======================
__global__ __launch_bounds__(256) void hist_k(const int* __restrict__ rec, int* __restrict__ cnt)
{
    int e = blockIdx.x*256 + threadIdx.x;
    if (e < NE) atomicAdd(&cnt[rec[e]], 1);
}

__global__ __launch_bounds__(1024) void scan_k(const int* __restrict__ cnt, int* __restrict__ rowptr)
{
    __shared__ int sdata[1024];
    __shared__ int s_carry;
    int tid = threadIdx.x;
    if (tid == 0) { s_carry = 0; rowptr[0] = 0; }
    __syncthreads();
    for (int base = 0; base < NN; base += 1024) {
        int i = base + tid;
        int v = (i < NN) ? cnt[i] : 0;
        sdata[tid] = v;
        __syncthreads();
        for (int off = 1; off < 1024; off <<= 1) {
            int t = (tid >= off) ? sdata[tid - off] : 0;
            __syncthreads();
            sdata[tid] += t;
            __syncthreads();
        }
        int total = sdata[1023];
        if (i < NN) rowptr[i + 1] = s_carry + sdata[tid];
        __syncthreads();
        if (tid == 0) s_carry += total;
        __syncthreads();
    }
}

__global__ __launch_bounds__(256) void scatter_k(const int* __restrict__ rec,
    const int* __restrict__ rowptr, int* __restrict__ cursor,
    int* __restrict__ colidx, int* __restrict__ seg)
{
    int e = blockIdx.x*256 + threadIdx.x;
    if (e < NE) {
        int r = rec[e];
        int pos = atomicAdd(&cursor[r], 1);
        colidx[rowptr[r] + pos] = e;
        seg[rowptr[r] + pos] = r;
    }
}

// ======================= E1: gather-reduce A_send[s(j)] -> haggf ==========
__global__ __launch_bounds__(256) void e1_k(const bf16* __restrict__ As,
    const int* __restrict__ send, const int* __restrict__ gmap,
    const int* __restrict__ seg, float* __restrict__ haggf)
{
    __shared__ int s_ids[256];
    __shared__ int s_seg[256];
    int tid = threadIdx.x, lane = tid & 63, wv = tid >> 6;
    int gbase = blockIdx.x*256;
    s_ids[tid] = send[gmap[gbase + tid]];
    s_seg[tid] = seg[gbase + tid];
    __syncthreads();
    int j0 = wv*64;
    float acc = 0.f;
    int cur = s_seg[j0];
    #pragma unroll 8
    for (int jj = 0; jj < 64; ++jj) {
        int n = s_seg[j0 + jj];
        if (n != cur) { atomicAdd(&haggf[(long)cur*64 + lane], acc); acc = 0.f; cur = n; }
        acc += __bfloat162float(As[(long)s_ids[j0 + jj]*64 + lane]);
    }
    atomicAdd(&haggf[(long)cur*64 + lane], acc);
}

// ======================= E2: e update + p_msg agg + next-layer A_e agg ====
// 128 edges/block, 4 waves x 32 edges (2 M-tiles of 16).
template <bool HASNEXT>
__global__ __launch_bounds__(256) void e2_k(
    const bf16* __restrict__ BCs, const bf16* __restrict__ Br, bf16* __restrict__ e_buf,
    const int* __restrict__ send, const int* __restrict__ seg, const int* __restrict__ gmap,
    const int* __restrict__ rowptr,
    const bf16* __restrict__ wCEU, const bf16* __restrict__ wCPM, const bf16* __restrict__ wHM3n,
    const float* __restrict__ eu_b,
    float* __restrict__ paggf, float* __restrict__ haggf)
{
    __shared__ __align__(16) bf16 sE[128 * AGG_STRIDE];   // 18432 B
    int tid = threadIdx.x, lane = tid & 63, wv = tid >> 6;
    int l15 = lane & 15, q = lane >> 4;
    int row0 = blockIdx.x*128;
    int wbase = row0 + wv*32;

    int erow[2], sidx[2], ridx[2];
    #pragma unroll
    for (int et = 0; et < 2; ++et) {
        int rc = wbase + et*16 + l15;
        erow[et] = rc;
        sidx[et] = send[gmap[rc]];
        ridx[et] = seg[rc];
    }

    // ---------- phase A: e_new = [B_s[s] | B_r[r] | e] @ CEU + eu_b ----------
    f32x4 acc[2][4];
    {
        float bv[4];
        #pragma unroll
        for (int t = 0; t < 4; ++t) bv[t] = eu_b[t*16 + l15];
        #pragma unroll
        for (int et = 0; et < 2; ++et)
            #pragma unroll
            for (int t = 0; t < 4; ++t) {
                acc[et][t][0]=bv[t]; acc[et][t][1]=bv[t]; acc[et][t][2]=bv[t]; acc[et][t][3]=bv[t];
            }
        #pragma unroll
        for (int c = 0; c < 6; ++c) {
            bf16x8s af[2];
            #pragma unroll
            for (int et = 0; et < 2; ++et) {
                if (c < 2)      af[et] = *(const bf16x8s*)(BCs + (long)sidx[et]*128 + c*32 + q*8);
                else if (c < 4) af[et] = *(const bf16x8s*)(Br  + (long)ridx[et]*64 + (c-2)*32 + q*8);
                else            af[et] = *(const bf16x8s*)(e_buf + (long)erow[et]*64 + (c-4)*32 + q*8);
            }
            #pragma unroll
            for (int t = 0; t < 4; ++t) {
                bf16x8s bfv = bfrag(wCEU, c, t, lane);
                #pragma unroll
                for (int et = 0; et < 2; ++et)
                    acc[et][t] = __builtin_amdgcn_mfma_f32_16x16x32_bf16(af[et], bfv, acc[et][t], 0, 0, 0);
            }
        }
    }
    // write e_new (global + LDS, stride-72 tile)
    #pragma unroll
    for (int et = 0; et < 2; ++et)
        #pragma unroll
        for (int r = 0; r < 4; ++r) {
            int lr = wv*32 + et*16 + q*4 + r;
            #pragma unroll
            for (int t = 0; t < 4; ++t) {
                bf16 v = __float2bfloat16(acc[et][t][r]);
                sE[lr*AGG_STRIDE + t*16 + l15] = v;
                e_buf[(long)(row0 + lr)*64 + t*16 + l15] = v;
            }
        }
    __syncthreads();

    // ---------- phase B: p_t = [C_s[s] | e_new] @ CPM (bias deg-handled in nup);
    //            a2 = e_new @ W3HMnext ----------
    f32x4 accP[2][4], accH[2][4];
    {
        #pragma unroll
        for (int et = 0; et < 2; ++et)
            #pragma unroll
            for (int t = 0; t < 4; ++t) {
                accP[et][t][0]=0; accP[et][t][1]=0; accP[et][t][2]=0; accP[et][t][3]=0;
                if (HASNEXT) { accH[et][t][0]=0; accH[et][t][1]=0; accH[et][t][2]=0; accH[et][t][3]=0; }
            }
        #pragma unroll
        for (int c = 0; c < 4; ++c) {
            bf16x8s af[2];
            #pragma unroll
            for (int et = 0; et < 2; ++et) {
                if (c < 2) af[et] = *(const bf16x8s*)(BCs + (long)sidx[et]*128 + 64 + c*32 + q*8);
                else       af[et] = *(const bf16x8s*)(sE + (wv*32 + et*16 + l15)*AGG_STRIDE + (c-2)*32 + q*8);
            }
            #pragma unroll
            for (int t = 0; t < 4; ++t) {
                bf16x8s bfv = bfrag(wCPM, c, t, lane);
                #pragma unroll
                for (int et = 0; et < 2; ++et)
                    accP[et][t] = __builtin_amdgcn_mfma_f32_16x16x32_bf16(af[et], bfv, accP[et][t], 0, 0, 0);
            }
            if (HASNEXT && c >= 2) {
                #pragma unroll
                for (int t = 0; t < 4; ++t) {
                    bf16x8s bfv = bfrag(wHM3n, c-2, t, lane);
                    #pragma unroll
                    for (int et = 0; et < 2; ++et)
                        accH[et][t] = __builtin_amdgcn_mfma_f32_16x16x32_bf16(af[et], bfv, accH[et][t], 0, 0, 0);
                }
            }
        }
    }
    __syncthreads();   // sE e_new reads done

    int col = tid & 63, wpart = tid >> 6;
    int n0 = seg[row0], n1 = seg[row0 + 127];

    // p_t -> paggf
    #pragma unroll
    for (int et = 0; et < 2; ++et)
        #pragma unroll
        for (int r = 0; r < 4; ++r)
            #pragma unroll
            for (int t = 0; t < 4; ++t)
                sE[(wv*32 + et*16 + q*4 + r)*AGG_STRIDE + t*16 + l15] = __float2bfloat16(accP[et][t][r]);
    __syncthreads();
    for (int n = n0 + wpart; n <= n1; n += 4) {
        int beg = rowptr[n], end = rowptr[n + 1];
        if (beg < row0) beg = row0;
        if (end > row0 + 128) end = row0 + 128;
        if (beg < end) {
            float s = 0.f;
            for (int j = beg; j < end; ++j) s += __bfloat162float(sE[(j - row0)*AGG_STRIDE + col]);
            atomicAdd(&paggf[(long)n*64 + col], s);
        }
    }
    if (HASNEXT) {
        __syncthreads();
        #pragma unroll
        for (int et = 0; et < 2; ++et)
            #pragma unroll
            for (int r = 0; r < 4; ++r)
                #pragma unroll
                for (int t = 0; t < 4; ++t)
                    sE[(wv*32 + et*16 + q*4 + r)*AGG_STRIDE + t*16 + l15] = __float2bfloat16(accH[et][t][r]);
        __syncthreads();
        for (int n = n0 + wpart; n <= n1; n += 4) {
            int beg = rowptr[n], end = rowptr[n + 1];
            if (beg < row0) beg = row0;
            if (end > row0 + 128) end = row0 + 128;
            if (beg < end) {
                float s = 0.f;
                for (int j = beg; j < end; ++j) s += __bfloat162float(sE[(j - row0)*AGG_STRIDE + col]);
                atomicAdd(&haggf[(long)n*64 + col], s);
            }
        }
    }
}

// ======================= eemb: e0 embed + bootstrap A_e agg ==============
__global__ __launch_bounds__(256) void eemb_k(
    const float* __restrict__ e_in, const int* __restrict__ gmap,
    const int* __restrict__ seg, const int* __restrict__ rowptr,
    const bf16* __restrict__ wEE, const bf16* __restrict__ wHM3,
    const float* __restrict__ ee_b, float* __restrict__ haggf, bf16* __restrict__ e_buf)
{
    __shared__ __align__(16) bf16 sE[128 * AGG_STRIDE];
    int tid = threadIdx.x, lane = tid & 63, wv = tid >> 6;
    int l15 = lane & 15, q = lane >> 4;
    int row0 = blockIdx.x*128;

    int em[2];
    #pragma unroll
    for (int et = 0; et < 2; ++et) em[et] = gmap[row0 + wv*32 + et*16 + l15];

    f32x4 acc[2][4];
    float bv[4];
    #pragma unroll
    for (int t = 0; t < 4; ++t) bv[t] = ee_b[t*16 + l15];
    #pragma unroll
    for (int et = 0; et < 2; ++et)
        #pragma unroll
        for (int t = 0; t < 4; ++t) {
            acc[et][t][0]=bv[t]; acc[et][t][1]=bv[t]; acc[et][t][2]=bv[t]; acc[et][t][3]=bv[t];
        }
    {   // K=32 (rows 0..15 real, padded)
        bf16x8s af[2];
        #pragma unroll
        for (int et = 0; et < 2; ++et) {
            bf16x8s v = {0,0,0,0,0,0,0,0};
            if (q < 2) v = cvt8(e_in + (long)em[et]*16 + q*8);
            af[et] = v;
        }
        #pragma unroll
        for (int t = 0; t < 4; ++t) {
            bf16x8s bfv = bfrag(wEE, 0, t, lane);
            #pragma unroll
            for (int et = 0; et < 2; ++et)
                acc[et][t] = __builtin_amdgcn_mfma_f32_16x16x32_bf16(af[et], bfv, acc[et][t], 0, 0, 0);
        }
    }
    #pragma unroll
    for (int et = 0; et < 2; ++et)
        #pragma unroll
        for (int r = 0; r < 4; ++r) {
            int lr = wv*32 + et*16 + q*4 + r;
            #pragma unroll
            for (int t = 0; t < 4; ++t) {
                bf16 v = __float2bfloat16(acc[et][t][r]);
                sE[lr*AGG_STRIDE + t*16 + l15] = v;
                e_buf[(long)(row0 + lr)*64 + t*16 + l15] = v;
            }
        }
    __syncthreads();

    // a2 = e0 @ W3HM[0]
    f32x4 accH[2][4];
    #pragma unroll
    for (int et = 0; et < 2; ++et)
        #pragma unroll
        for (int t = 0; t < 4; ++t) { accH[et][t][0]=0; accH[et][t][1]=0; accH[et][t][2]=0; accH[et][t][3]=0; }
    #pragma unroll
    for (int c = 0; c < 2; ++c) {
        bf16x8s af[2];
        #pragma unroll
        for (int et = 0; et < 2; ++et)
            af[et] = *(const bf16x8s*)(sE + (wv*32 + et*16 + l15)*AGG_STRIDE + c*32 + q*8);
        #pragma unroll
        for (int t = 0; t < 4; ++t) {
            bf16x8s bfv = bfrag(wHM3, c, t, lane);
            #pragma unroll
            for (int et = 0; et < 2; ++et)
                accH[et][t] = __builtin_amdgcn_mfma_f32_16x16x32_bf16(af[et], bfv, accH[et][t], 0, 0, 0);
        }
    }
    __syncthreads();
    #pragma unroll
    for (int et = 0; et < 2; ++et)
        #pragma unroll
        for (int r = 0; r < 4; ++r)
            #pragma unroll
            for (int t = 0; t < 4; ++t)
                sE[(wv*32 + et*16 + q*4 + r)*AGG_STRIDE + t*16 + l15] = __float2bfloat16(accH[et][t][r]);
    __syncthreads();
    int col = tid & 63, wpart = tid >> 6;
    int n0 = seg[row0], n1 = seg[row0 + 127];
    for (int n = n0 + wpart; n <= n1; n += 4) {
        int beg = rowptr[n], end = rowptr[n + 1];
        if (beg < row0) beg = row0;
        if (end > row0 + 128) end = row0 + 128;
        if (beg < end) {
            float s = 0.f;
            for (int j = beg; j < end; ++j) s += __bfloat162float(sE[(j - row0)*AGG_STRIDE + col]);
            atomicAdd(&haggf[(long)n*64 + col], s);
        }
    }
}

// ======================= node kernels (64 rows/block, 16 rows/wave) ======
__global__ __launch_bounds__(256) void hemb_k(const float* __restrict__ h_in,
    const bf16* __restrict__ wHE, const float* __restrict__ he_b, bf16* __restrict__ h)
{
    int tid = threadIdx.x, lane = tid & 63, wv = tid >> 6;
    int l15 = lane & 15, q = lane >> 4;
    int row = blockIdx.x*64 + wv*16 + l15;
    int rc = (row < NN) ? row : NN - 1;
    f32x4 acc[4];
    #pragma unroll
    for (int t = 0; t < 4; ++t) { float b = he_b[t*16 + l15]; acc[t][0]=b; acc[t][1]=b; acc[t][2]=b; acc[t][3]=b; }
    #pragma unroll
    for (int c = 0; c < 4; ++c) {
        bf16x8s af = cvt8(h_in + (long)rc*128 + c*32 + q*8);
        #pragma unroll
        for (int t = 0; t < 4; ++t)
            acc[t] = __builtin_amdgcn_mfma_f32_16x16x32_bf16(af, bfrag(wHE, c, t, lane), acc[t], 0, 0, 0);
    }
    #pragma unroll
    for (int r = 0; r < 4; ++r) {
        int ro = blockIdx.x*64 + wv*16 + q*4 + r;
        if (ro < NN)
            #pragma unroll
            for (int t = 0; t < 4; ++t) h[(long)ro*64 + t*16 + l15] = __float2bfloat16(acc[t][r]);
    }
}

__global__ __launch_bounds__(256) void pemb_k(const float* __restrict__ p_in,
    const bf16* __restrict__ wPE, const float* __restrict__ pe_b, bf16* __restrict__ p)
{
    int tid = threadIdx.x, lane = tid & 63, wv = tid >> 6;
    int l15 = lane & 15, q = lane >> 4;
    int row = blockIdx.x*64 + wv*16 + l15;
    int rc = (row < NN) ? row : NN - 1;
    f32x4 acc[4];
    #pragma unroll
    for (int t = 0; t < 4; ++t) { float b = pe_b[t*16 + l15]; acc[t][0]=b; acc[t][1]=b; acc[t][2]=b; acc[t][3]=b; }
    {
        bf16x8s af = {0,0,0,0,0,0,0,0};
        if (q < 2) af = cvt8(p_in + (long)rc*16 + q*8);
        #pragma unroll
        for (int t = 0; t < 4; ++t)
            acc[t] = __builtin_amdgcn_mfma_f32_16x16x32_bf16(af, bfrag(wPE, 0, t, lane), acc[t], 0, 0, 0);
    }
    #pragma unroll
    for (int r = 0; r < 4; ++r) {
        int ro = blockIdx.x*64 + wv*16 + q*4 + r;
        if (ro < NN)
            #pragma unroll
            for (int t = 0; t < 4; ++t) p[(long)ro*64 + t*16 + l15] = __float2bfloat16(acc[t][r]);
    }
}

// N1: A_send (bf16), A_rec (fp32); C_s (bf16 -> BCs upper), C_r (fp32)
__global__ __launch_bounds__(256) void n1_k(const bf16* __restrict__ h, const bf16* __restrict__ p,
    const bf16* __restrict__ wHMs, const bf16* __restrict__ wHMr,
    const bf16* __restrict__ wPMs, const bf16* __restrict__ wPMr,
    bf16* __restrict__ As, float* __restrict__ Arf, bf16* __restrict__ BCs, float* __restrict__ Crf)
{
    int tid = threadIdx.x, lane = tid & 63, wv = tid >> 6;
    int l15 = lane & 15, q = lane >> 4;
    int row = blockIdx.x*64 + wv*16 + l15;
    int rc = (row < NN) ? row : NN - 1;
    f32x4 aAs[4], aAr[4], aCs[4], aCr[4];
    #pragma unroll
    for (int t = 0; t < 4; ++t) {
        aAs[t][0]=0;aAs[t][1]=0;aAs[t][2]=0;aAs[t][3]=0;
        aAr[t][0]=0;aAr[t][1]=0;aAr[t][2]=0;aAr[t][3]=0;
        aCs[t][0]=0;aCs[t][1]=0;aCs[t][2]=0;aCs[t][3]=0;
        aCr[t][0]=0;aCr[t][1]=0;aCr[t][2]=0;aCr[t][3]=0;
    }
    #pragma unroll
    for (int c = 0; c < 4; ++c) {
        bf16x8s af = (c < 2) ? *(const bf16x8s*)(h + (long)rc*64 + c*32 + q*8)
                             : *(const bf16x8s*)(p + (long)rc*64 + (c-2)*32 + q*8);
        #pragma unroll
        for (int t = 0; t < 4; ++t) {
            aAs[t] = __builtin_amdgcn_mfma_f32_16x16x32_bf16(af, bfrag(wHMs, c, t, lane), aAs[t], 0, 0, 0);
            aAr[t] = __builtin_amdgcn_mfma_f32_16x16x32_bf16(af, bfrag(wHMr, c, t, lane), aAr[t], 0, 0, 0);
        }
        if (c >= 2) {
            #pragma unroll
            for (int t = 0; t < 4; ++t) {
                aCs[t] = __builtin_amdgcn_mfma_f32_16x16x32_bf16(af, bfrag(wPMs, c-2, t, lane), aCs[t], 0, 0, 0);
                aCr[t] = __builtin_amdgcn_mfma_f32_16x16x32_bf16(af, bfrag(wPMr, c-2, t, lane), aCr[t], 0, 0, 0);
            }
        }
    }
    #pragma unroll
    for (int r = 0; r < 4; ++r) {
        int ro = blockIdx.x*64 + wv*16 + q*4 + r;
        if (ro < NN) {
            #pragma unroll
            for (int t = 0; t < 4; ++t) {
                int col = t*16 + l15;
                As[(long)ro*64 + col]        = __float2bfloat16(aAs[t][r]);
                Arf[(long)ro*64 + col]       = aAr[t][r];
                BCs[(long)ro*128 + 64 + col] = __float2bfloat16(aCs[t][r]);
                Crf[(long)ro*64 + col]       = aCr[t][r];
            }
        }
    }
}

// N3: B_s (-> BCs lower half), B_r  (from h_new, K=64)
__global__ __launch_bounds__(256) void n3_k(const bf16* __restrict__ h,
    const bf16* __restrict__ wEUs, const bf16* __restrict__ wEUr,
    bf16* __restrict__ BCs, bf16* __restrict__ Br)
{
    int tid = threadIdx.x, lane = tid & 63, wv = tid >> 6;
    int l15 = lane & 15, q = lane >> 4;
    int row = blockIdx.x*64 + wv*16 + l15;
    int rc = (row < NN) ? row : NN - 1;
    f32x4 aBs[4], aBr[4];
    #pragma unroll
    for (int t = 0; t < 4; ++t) {
        aBs[t][0]=0;aBs[t][1]=0;aBs[t][2]=0;aBs[t][3]=0;
        aBr[t][0]=0;aBr[t][1]=0;aBr[t][2]=0;aBr[t][3]=0;
    }
    #pragma unroll
    for (int c = 0; c < 2; ++c) {
        bf16x8s af = *(const bf16x8s*)(h + (long)rc*64 + c*32 + q*8);
        #pragma unroll
        for (int t = 0; t < 4; ++t) {
            aBs[t] = __builtin_amdgcn_mfma_f32_16x16x32_bf16(af, bfrag(wEUs, c, t, lane), aBs[t], 0, 0, 0);
            aBr[t] = __builtin_amdgcn_mfma_f32_16x16x32_bf16(af, bfrag(wEUr, c, t, lane), aBr[t], 0, 0, 0);
        }
    }
    #pragma unroll
    for (int r = 0; r < 4; ++r) {
        int ro = blockIdx.x*64 + wv*16 + q*4 + r;
        if (ro < NN) {
            #pragma unroll
            for (int t = 0; t < 4; ++t) {
                int col = t*16 + l15;
                BCs[(long)ro*128 + col] = __float2bfloat16(aBs[t][r]);
                Br[(long)ro*64 + col]   = __float2bfloat16(aBr[t][r]);
            }
        }
    }
}

// N2/N4: x_new = [x | aggf + deg*(Rf + mb)] @ W + b   (Rf fp32: deg-amplified)
__global__ __launch_bounds__(256) void nup_k(const bf16* __restrict__ x,
    const float* __restrict__ aggf, const float* __restrict__ Rf, const int* __restrict__ deg,
    const float* __restrict__ mb, const bf16* __restrict__ wU, const float* __restrict__ ub,
    bf16* __restrict__ x_out, float* __restrict__ out2)
{
    int tid = threadIdx.x, lane = tid & 63, wv = tid >> 6;
    int l15 = lane & 15, q = lane >> 4;
    int row = blockIdx.x*64 + wv*16 + l15;
    int rc = (row < NN) ? row : NN - 1;
    float degf = (float)deg[rc];
    f32x4 acc[4];
    #pragma unroll
    for (int t = 0; t < 4; ++t) { float b = ub[t*16 + l15]; acc[t][0]=b; acc[t][1]=b; acc[t][2]=b; acc[t][3]=b; }
    #pragma unroll
    for (int c = 0; c < 4; ++c) {
        bf16x8s af;
        if (c < 2) {
            af = *(const bf16x8s*)(x + (long)rc*64 + c*32 + q*8);
        } else {
            int ch0 = (c-2)*32 + q*8;
            const float* ag = aggf + (long)rc*64 + ch0;
            const float* rr = Rf + (long)rc*64 + ch0;
            const float* bb = mb + ch0;
            bf16 tmp[8];
            #pragma unroll
            for (int u = 0; u < 8; ++u)
                tmp[u] = __float2bfloat16(ag[u] + degf*(rr[u] + bb[u]));
            af = *(const bf16x8s*)tmp;
        }
        #pragma unroll
        for (int t = 0; t < 4; ++t)
            acc[t] = __builtin_amdgcn_mfma_f32_16x16x32_bf16(af, bfrag(wU, c, t, lane), acc[t], 0, 0, 0);
    }
    #pragma unroll
    for (int r = 0; r < 4; ++r) {
        int ro = blockIdx.x*64 + wv*16 + q*4 + r;
        if (ro < NN) {
            #pragma unroll
            for (int t = 0; t < 4; ++t) {
                float fv = acc[t][r];
                x_out[(long)ro*64 + t*16 + l15] = __float2bfloat16(fv);
                if (out2) out2[(long)ro*64 + t*16 + l15] = fv;
            }
        }
    }
}

// ======================= launch =======================
extern "C" void kernel_launch(void* const* d_in, const int* in_sizes, int n_in,
                              void* d_out, int out_size, void* d_ws, size_t ws_size,
                              hipStream_t stream)
{
    (void)in_sizes; (void)n_in; (void)out_size; (void)ws_size;
    const float* h_in = (const float*)d_in[0];
    const float* e_in = (const float*)d_in[1];
    const float* p_in = (const float*)d_in[2];
    const int*  ei   = (const int*)d_in[3];
    const int* send = ei;
    const int* rec  = ei + NE;
    const float* he_W = (const float*)d_in[4];  const float* he_b = (const float*)d_in[5];
    const float* ee_W = (const float*)d_in[6];  const float* ee_b = (const float*)d_in[7];
    const float* pe_W = (const float*)d_in[8];  const float* pe_b = (const float*)d_in[9];
    const float* hm_W = (const float*)d_in[10]; const float* hm_b = (const float*)d_in[11];
    const float* hu_W = (const float*)d_in[12]; const float* hu_b = (const float*)d_in[13];
    const float* eu_W = (const float*)d_in[14]; const float* eu_b = (const float*)d_in[15];
    const float* pm_W = (const float*)d_in[16]; const float* pm_b = (const float*)d_in[17];
    const float* pu_W = (const float*)d_in[18]; const float* pu_b = (const float*)d_in[19];

    char* ws = (char*)d_ws;
    bf16* e_buf = (bf16*)(ws + OFF_E);
    bf16* As    = (bf16*)(ws + OFF_AS);
    float* Arf  = (float*)(ws + OFF_ARF);
    bf16* BCs   = (bf16*)(ws + OFF_BCS);
    bf16* Br    = (bf16*)(ws + OFF_BR);
    float* Crf  = (float*)(ws + OFF_CRF);
    bf16* h     = (bf16*)(ws + OFF_H);
    bf16* p     = (bf16*)(ws + OFF_P);
    float* haggf= (float*)(ws + OFF_HAGGF);
    float* paggf= (float*)(ws + OFF_PAGGF);
    bf16* wf    = (bf16*)(ws + OFF_WFMT);
    int* rowptr = (int*)(ws + OFF_ROWPTR);
    int* colidx = (int*)(ws + OFF_COLIDX);
    int* segarr = (int*)(ws + OFF_SEG);
    int* cnt    = (int*)(ws + OFF_CNT);
    float* dout = (float*)d_out;

    const int EB  = NE / 256;           // 3125
    const int EB2 = NE / 128;           // 6250
    const int NB64 = (NN + 63) / 64;    // 782

    // CSR build; cnt ends as deg
    (void)hipMemsetAsync(cnt, 0, NN * sizeof(int), stream);
    hist_k<<<EB, 256, 0, stream>>>(rec, cnt);
    scan_k<<<1, 1024, 0, stream>>>(cnt, rowptr);
    (void)hipMemsetAsync(cnt, 0, NN * sizeof(int), stream);
    scatter_k<<<EB, 256, 0, stream>>>(rec, rowptr, cnt, colidx, segarr);

    wfmt_k<<<47, 256, 0, stream>>>(he_W, ee_W, pe_W, hm_W, hu_W, eu_W, pm_W, pu_W, wf);

    (void)hipMemsetAsync(haggf, 0, (long)NN*64*sizeof(float), stream);
    (void)hipMemsetAsync(paggf, 0, (long)NN*64*sizeof(float), stream);

    // embeddings
    hemb_k<<<NB64, 256, 0, stream>>>(h_in, wf + FW_HE, he_b, h);
    pemb_k<<<NB64, 256, 0, stream>>>(p_in, wf + FW_PE, pe_b, p);
    eemb_k<<<EB2, 256, 0, stream>>>(e_in, colidx, segarr, rowptr,
        wf + FW_EE, wf + FW_L0 + R_W3HM, ee_b, haggf, e_buf);

    for (int i = 0; i < 4; ++i) {
        long base = FW_L0 + (long)i*LSTR;
        // N1: A_send, A_rec(fp32), C_s, C_r(fp32)
        n1_k<<<NB64, 256, 0, stream>>>(h, p,
            wf + base + R_HMS, wf + base + R_HMR, wf + base + R_PMS, wf + base + R_PMR,
            As, Arf, BCs, Crf);
        // E1: haggf += segsum(A_send[s])
        e1_k<<<EB, 256, 0, stream>>>(As, send, colidx, segarr, haggf);
        // N2: h_new = [h | haggf + deg*(A_rec + hm_b)] @ HU + hu_b
        nup_k<<<NB64, 256, 0, stream>>>(h, haggf, Arf, cnt, hm_b + i*64,
            wf + base + R_HU, hu_b + i*64, h, (i == 3) ? dout : nullptr);
        (void)hipMemsetAsync(haggf, 0, (long)NN*64*sizeof(float), stream);
        // N3: B_s, B_r from h_new
        n3_k<<<NB64, 256, 0, stream>>>(h, wf + base + R_EUS, wf + base + R_EUR, BCs, Br);
        // E2: e_new; paggf += segsum(C_s[s]+e_new@W3pm); haggf += segsum(e_new@W3hm[i+1])
        if (i < 3) {
            e2_k<true><<<EB2, 256, 0, stream>>>(BCs, Br, e_buf, send, segarr, colidx, rowptr,
                wf + base + R_CEU, wf + base + R_CPM, wf + base + LSTR + R_W3HM,
                eu_b + i*64, paggf, haggf);
        } else {
            e2_k<false><<<EB2, 256, 0, stream>>>(BCs, Br, e_buf, send, segarr, colidx, rowptr,
                wf + base + R_CEU, wf + base + R_CPM, nullptr,
                eu_b + i*64, paggf, haggf);
        }
        // N4: p_new = [p | paggf + deg*(C_r + pm_b)] @ PU + pu_b
        nup_k<<<NB64, 256, 0, stream>>>(p, paggf, Crf, cnt, pm_b + i*64,
            wf + base + R_PU, pu_b + i*64, p, (i == 3) ? dout + (long)NN*64 : nullptr);
        (void)hipMemsetAsync(paggf, 0, (long)NN*64*sizeof(float), stream);
    }
}